// Round 7
// baseline (2016.948 us; speedup 1.0000x reference)
//
#include <hip/hip_runtime.h>
#include <hip/hip_bf16.h>

#define B_ 2
#define S_ 1024
#define T_ (B_*S_)
#define D_ 2048
#define L_ 4
#define HQ_ 32
#define HKV_ 8
#define HD_ 64
#define I_ 5632
#define EPS_ 1e-5f
#define SCALE_ 0.125f

typedef __attribute__((ext_vector_type(4))) float  float4v;
typedef __attribute__((ext_vector_type(8))) short  short8v;

#define GLOAD16(g, l) \
  __builtin_amdgcn_global_load_lds((const __attribute__((address_space(1))) void*)(g), \
                                   (__attribute__((address_space(3))) void*)(l), 16, 0, 0)

__device__ __forceinline__ short f2bf(float f) {
  union { float f; unsigned u; } c; c.f = f;
  unsigned u = c.u + 0x7fffu + ((c.u >> 16) & 1u);
  return (short)(u >> 16);
}

// bijective XCD-aware block swizzle (m204), column-major decode
__device__ __forceinline__ void xcd_swizzle(int gx, int gy, int& bx, int& by) {
  int nwg = gx * gy;
  int orig = by * gx + bx;
  int q = nwg >> 3, r = nwg & 7;
  int xcd = orig & 7, loc = orig >> 3;
  int swz = (xcd < r ? xcd * (q + 1) : r * (q + 1) + (xcd - r) * q) + loc;
  bx = swz / gy;
  by = swz - bx * gy;
}

// ---------------- transpose f32 [K][N] -> bf16 [N][K], 64x64 vectorized ----------------
__global__ __launch_bounds__(256)
void transpose_bf16(const float* __restrict__ in, short* __restrict__ out,
                    int K, int N) {
  __shared__ float t[64][65];
  const int bx = blockIdx.x * 64;   // N
  const int by = blockIdx.y * 64;   // K
  const int tid = threadIdx.x;
  const int lr = tid >> 4;
  const int lc = (tid & 15) * 4;
  #pragma unroll
  for (int j = 0; j < 64; j += 16) {
    float4v v = *(const float4v*)(in + (size_t)(by + lr + j) * N + bx + lc);
    t[lr + j][lc] = v[0]; t[lr + j][lc + 1] = v[1];
    t[lr + j][lc + 2] = v[2]; t[lr + j][lc + 3] = v[3];
  }
  __syncthreads();
  const int nr = tid >> 3;
  const int kc = (tid & 7) * 8;
  #pragma unroll
  for (int j = 0; j < 64; j += 32) {
    short8v y;
    #pragma unroll
    for (int e = 0; e < 8; e++) y[e] = f2bf(t[kc + e][nr + j]);
    *(short8v*)(out + (size_t)(bx + nr + j) * K + by + kc) = y;
  }
}

// ---------------- embedding gather ----------------
__global__ __launch_bounds__(256)
void embed_gather(const int* __restrict__ ids, const float* __restrict__ embed,
                  float* __restrict__ h) {
  size_t i = (size_t)blockIdx.x * 256 + threadIdx.x;
  int t  = (int)(i >> 9);
  int d4 = (int)(i & 511);
  ((float4v*)h)[i] = ((const float4v*)(embed + (size_t)ids[t] * D_))[d4];
}

// ---------------- fused residual-add + RMSNorm (bf16 or f32 out) ----------------
__global__ __launch_bounds__(256)
void rmsnorm_add(const float* __restrict__ x, float* __restrict__ res,
                 const float* __restrict__ w, void* __restrict__ outp,
                 int first, int bf16out) {
  const int row = blockIdx.x;
  const int tid = threadIdx.x;
  const size_t base = (size_t)row * D_;
  float4v v0 = ((const float4v*)(x + base))[tid * 2];
  float4v v1 = ((const float4v*)(x + base))[tid * 2 + 1];
  if (!first) {
    v0 += ((const float4v*)(res + base))[tid * 2];
    v1 += ((const float4v*)(res + base))[tid * 2 + 1];
  }
  ((float4v*)(res + base))[tid * 2]     = v0;
  ((float4v*)(res + base))[tid * 2 + 1] = v1;
  float ss = v0[0]*v0[0] + v0[1]*v0[1] + v0[2]*v0[2] + v0[3]*v0[3]
           + v1[0]*v1[0] + v1[1]*v1[1] + v1[2]*v1[2] + v1[3]*v1[3];
  #pragma unroll
  for (int off = 32; off > 0; off >>= 1) ss += __shfl_xor(ss, off, 64);
  __shared__ float red[4];
  if ((tid & 63) == 0) red[tid >> 6] = ss;
  __syncthreads();
  float tot = red[0] + red[1] + red[2] + red[3];
  float rs = rsqrtf(tot * (1.0f / D_) + EPS_);
  float4v w0 = ((const float4v*)w)[tid * 2];
  float4v w1 = ((const float4v*)w)[tid * 2 + 1];
  float4v o0 = v0 * rs * w0;
  float4v o1 = v1 * rs * w1;
  if (bf16out) {
    short8v y;
    #pragma unroll
    for (int k = 0; k < 4; k++) { y[k] = f2bf(o0[k]); y[k + 4] = f2bf(o1[k]); }
    ((short8v*)((char*)outp + base * 2))[tid] = y;
  } else {
    float* op = (float*)outp + base;
    ((float4v*)op)[tid * 2]     = o0;
    ((float4v*)op)[tid * 2 + 1] = o1;
  }
}

#define BM 128
#define BN 128
#define BKS 32

// ======== 128x256 8-wave GEMM: T2 swizzle + counted vmcnt(6) + setprio ========
// C[M][N] f32 = A[M][K] bf16 x Bt[N][K] bf16.  BK=64, 512 thr, wave tile 64x64.
// LDS 96KB dbuf.  LDS elem (row, G*8+j) holds global col (G^(row&7))*8+j;
// read of global group Gg=ks*4+g comes from LDS group Gg^(fr&7)  [rule #21].
__global__ __launch_bounds__(512, 2)
void gemm_big(const short* __restrict__ A, const short* __restrict__ Bt,
              float* __restrict__ C, int M, int N, int K) {
  __shared__ short sA[2][128 * 64];
  __shared__ short sB[2][256 * 64];
  int bx = blockIdx.x, by = blockIdx.y;
  xcd_swizzle(gridDim.x, gridDim.y, bx, by);
  const int tid  = threadIdx.x;
  const int lane = tid & 63;
  const int wv   = tid >> 6;
  const int wr   = wv >> 2;          // 0..1 (M half)
  const int wc   = wv & 3;           // 0..3 (N quarter)
  const int row0 = by * 128;
  const int col0 = bx * 256;
  const int fr = lane & 15;
  const int g  = lane >> 4;
  const int NT = K >> 6;

  float4v acc[4][4] = {};            // 64 VGPR

  // staging slots: slot s -> LDS elems [s*8, s*8+8), row = s>>3, group = s&7
  int rA[2], cA[2], rB[4], cB[4];
  #pragma unroll
  for (int k = 0; k < 2; k++) {
    int s = tid + k * 512;
    rA[k] = s >> 3;
    cA[k] = (((s & 7) ^ (rA[k] & 7)) << 3);   // pre-swizzled source col
  }
  #pragma unroll
  for (int k = 0; k < 4; k++) {
    int s = tid + k * 512;
    rB[k] = s >> 3;
    cB[k] = (((s & 7) ^ (rB[k] & 7)) << 3);
  }

#define STAGEBIG(t, buf) do { \
    int k0_ = (t) << 6; \
    _Pragma("unroll") \
    for (int k_ = 0; k_ < 2; k_++) \
      GLOAD16(A  + (size_t)(row0 + rA[k_]) * K + k0_ + cA[k_], \
              &sA[buf][(tid + k_ * 512) * 8]); \
    _Pragma("unroll") \
    for (int k_ = 0; k_ < 4; k_++) \
      GLOAD16(Bt + (size_t)(col0 + rB[k_]) * K + k0_ + cB[k_], \
              &sB[buf][(tid + k_ * 512) * 8]); \
  } while (0)

  STAGEBIG(0, 0);                    // prologue: tile 0 -> buf0

  for (int t = 0; t < NT; t++) {
    const int cur = t & 1;
    if (t + 1 < NT) {
      STAGEBIG(t + 1, cur ^ 1);      // 6 new loads in flight across this tile's MFMA
      asm volatile("s_waitcnt vmcnt(6)" ::: "memory");   // oldest 6 (= tile t) done
    } else {
      asm volatile("s_waitcnt vmcnt(0)" ::: "memory");
    }
    __builtin_amdgcn_s_barrier();    // all waves' tile-t loads resident
    __builtin_amdgcn_sched_barrier(0);

    const short* pA = &sA[cur][(wr * 64) * 64];
    const short* pB = &sB[cur][(wc * 64) * 64];
    #pragma unroll
    for (int ks = 0; ks < 2; ks++) {
      const int fswk = ((((ks << 2) | g) ^ (fr & 7)) << 3);   // in [0,64)
      short8v bfr[4], afr[4];
      #pragma unroll
      for (int ni = 0; ni < 4; ni++)
        bfr[ni] = *(const short8v*)(pB + (ni * 16 + fr) * 64 + fswk);
      #pragma unroll
      for (int m4 = 0; m4 < 4; m4++)
        afr[m4] = *(const short8v*)(pA + (m4 * 16 + fr) * 64 + fswk);
      __builtin_amdgcn_s_setprio(1);
      #pragma unroll
      for (int m4 = 0; m4 < 4; m4++)
        #pragma unroll
        for (int ni = 0; ni < 4; ni++)
          acc[m4][ni] = __builtin_amdgcn_mfma_f32_16x16x32_bf16(
              afr[m4], bfr[ni], acc[m4][ni], 0, 0, 0);
      __builtin_amdgcn_s_setprio(0);
    }
    asm volatile("" ::: "memory");
    __builtin_amdgcn_s_barrier();    // all waves done reading buf[cur] before overwrite
  }

  #pragma unroll
  for (int m4 = 0; m4 < 4; m4++)
    #pragma unroll
    for (int ni = 0; ni < 4; ni++) {
      size_t base = (size_t)(row0 + wr * 64 + m4 * 16 + g * 4) * N
                    + col0 + wc * 64 + ni * 16 + fr;
      #pragma unroll
      for (int r = 0; r < 4; r++)
        C[base + (size_t)r * N] = acc[m4][ni][r];
    }
#undef STAGEBIG
}

// ------- plain GEMM, BN=64 (o-proj / down-proj shapes) -------
__global__ __launch_bounds__(256)
void gemm_n64(const short* __restrict__ A, const short* __restrict__ Bt,
              float* __restrict__ C, int M, int N, int K) {
  __shared__ short sA[BM * BKS];
  __shared__ short sB[64 * BKS];
  int bx = blockIdx.x, by = blockIdx.y;
  xcd_swizzle(gridDim.x, gridDim.y, bx, by);
  const int tid  = threadIdx.x;
  const int lane = tid & 63;
  const int wave = tid >> 6;
  const int wm = (wave >> 1) << 6;
  const int wn = (wave & 1) << 5;
  const int row0 = by * BM;
  const int col0 = bx * 64;
  const int fr = lane & 15;
  const int fk = (lane >> 4) << 3;
  float4v acc[4][2] = {};

  const int r_st  = tid >> 2;
  const int kc_st = (tid & 3) << 3;
  const short* pA = A  + (size_t)(row0 + r_st) * K + kc_st;
  const short* pB = Bt + (size_t)(col0 + r_st) * K + kc_st;
  const size_t stride64 = (size_t)64 * K;
  short* lA0 = &sA[tid * 8];
  short* lA1 = &sA[(256 + tid) * 8];
  short* lB0 = &sB[tid * 8];

  for (int k0 = 0; k0 < K; k0 += BKS) {
    GLOAD16(pA, lA0);
    GLOAD16(pA + stride64, lA1);
    GLOAD16(pB, lB0);
    pA += BKS; pB += BKS;
    __syncthreads();
    short8v af[4], bfr[2];
    #pragma unroll
    for (int f = 0; f < 4; f++)
      af[f] = *(const short8v*)(&sA[(wm + f * 16 + fr) * BKS + fk]);
    #pragma unroll
    for (int f = 0; f < 2; f++)
      bfr[f] = *(const short8v*)(&sB[(wn + f * 16 + fr) * BKS + fk]);
    #pragma unroll
    for (int i = 0; i < 4; i++)
      #pragma unroll
      for (int j = 0; j < 2; j++)
        acc[i][j] = __builtin_amdgcn_mfma_f32_16x16x32_bf16(af[i], bfr[j], acc[i][j], 0, 0, 0);
    __syncthreads();
  }
  const int cr = (lane >> 4) << 2;
  const int cc = lane & 15;
  #pragma unroll
  for (int i = 0; i < 4; i++)
    #pragma unroll
    for (int j = 0; j < 2; j++) {
      size_t base = (size_t)(row0 + wm + i * 16 + cr) * N + col0 + wn + j * 16 + cc;
      #pragma unroll
      for (int r = 0; r < 4; r++)
        C[base + (size_t)r * N] = acc[i][j][r];
    }
}

// ------- QKV GEMM with fused RoPE epilogue (128x128, proven) -------
__global__ __launch_bounds__(256)
void gemm_qkv_rope(const short* __restrict__ A, const short* __restrict__ Bt,
                   const float* __restrict__ tab, short* __restrict__ qbf,
                   short* __restrict__ kbf, short* __restrict__ vbf, int K) {
  __shared__ short sA[BM * BKS];
  __shared__ short sB[BN * BKS];
  int bx = blockIdx.x, by = blockIdx.y;
  xcd_swizzle(gridDim.x, gridDim.y, bx, by);
  const int tid  = threadIdx.x;
  const int lane = tid & 63;
  const int wave = tid >> 6;
  const int wm = (wave >> 1) << 6;
  const int wn = (wave & 1) << 6;
  const int row0 = by * BM;
  const int col0 = bx * BN;
  const int fr = lane & 15;
  const int fk = (lane >> 4) << 3;
  float4v acc[4][4] = {};

  const int r_st  = tid >> 2;
  const int kc_st = (tid & 3) << 3;
  const short* pA = A  + (size_t)(row0 + r_st) * K + kc_st;
  const short* pB = Bt + (size_t)(col0 + r_st) * K + kc_st;
  const size_t stride64 = (size_t)64 * K;
  short* lA0 = &sA[tid * 8];
  short* lA1 = &sA[(256 + tid) * 8];
  short* lB0 = &sB[tid * 8];
  short* lB1 = &sB[(256 + tid) * 8];

  for (int k0 = 0; k0 < K; k0 += BKS) {
    GLOAD16(pA, lA0);
    GLOAD16(pA + stride64, lA1);
    GLOAD16(pB, lB0);
    GLOAD16(pB + stride64, lB1);
    pA += BKS; pB += BKS;
    __syncthreads();
    short8v af[4], bfr[4];
    #pragma unroll
    for (int f = 0; f < 4; f++) {
      af[f]  = *(const short8v*)(&sA[(wm + f * 16 + fr) * BKS + fk]);
      bfr[f] = *(const short8v*)(&sB[(wn + f * 16 + fr) * BKS + fk]);
    }
    #pragma unroll
    for (int i = 0; i < 4; i++)
      #pragma unroll
      for (int j = 0; j < 4; j++)
        acc[i][j] = __builtin_amdgcn_mfma_f32_16x16x32_bf16(af[i], bfr[j], acc[i][j], 0, 0, 0);
    __syncthreads();
  }
  const int cr = (lane >> 4) << 2;
  const int cc = lane & 15;
  const int head = (col0 + wn) >> 6;

  if (head < HQ_ + HKV_) {
    const float sc = (head < HQ_) ? SCALE_ : 1.0f;
    #pragma unroll
    for (int i = 0; i < 4; i++)
      #pragma unroll
      for (int jj = 0; jj < 2; jj++)
        #pragma unroll
        for (int r = 0; r < 4; r++) {
          int m = row0 + wm + i * 16 + cr + r;
          int b = m >> 10, s = m & (S_ - 1);
          int d1 = jj * 16 + cc;
          float x1 = acc[i][jj][r], x2 = acc[i][jj + 2][r];
          const float* tb = tab + (size_t)m * 64 + d1 * 2;
          float c = tb[0], sn = tb[1];
          short y1 = f2bf((x1 * c - x2 * sn) * sc);
          short y2 = f2bf((x2 * c + x1 * sn) * sc);
          size_t base;
          if (head < HQ_)
            base = ((size_t)((b * HQ_ + head) * S_ + s)) * HD_;
          else
            base = ((size_t)((b * HKV_ + head - HQ_) * S_ + s)) * HD_;
          short* dst = (head < HQ_) ? qbf : kbf;
          dst[base + d1]      = y1;
          dst[base + d1 + 32] = y2;
        }
  } else {
    const int vh = head - HQ_ - HKV_;
    #pragma unroll
    for (int i = 0; i < 4; i++)
      #pragma unroll
      for (int j = 0; j < 4; j++)
        #pragma unroll
        for (int r = 0; r < 4; r++) {
          int m = row0 + wm + i * 16 + cr + r;
          int b = m >> 10, s = m & (S_ - 1);
          vbf[((size_t)((b * HKV_ + vh) * S_ + s)) * HD_ + j * 16 + cc] =
              f2bf(acc[i][j][r]);
        }
  }
}

// ---------------- SwiGLU (f32 in, bf16 out) ----------------
__global__ __launch_bounds__(256)
void swiglu_kernel(const float* __restrict__ gu, short* __restrict__ mlp) {
  size_t i = (size_t)blockIdx.x * 256 + threadIdx.x;   // over T*I/8
  size_t t = i / 704;
  int c = (int)(i - t * 704);
  const float* gp = gu + t * 11264 + c * 8;
  const float* up = gp + 5632;
  float4v g0 = *(const float4v*)gp, g1 = *(const float4v*)(gp + 4);
  float4v u0 = *(const float4v*)up, u1 = *(const float4v*)(up + 4);
  short8v r;
  #pragma unroll
  for (int k = 0; k < 4; k++) {
    r[k]     = f2bf(g0[k] / (1.0f + __expf(-g0[k])) * u0[k]);
    r[k + 4] = f2bf(g1[k] / (1.0f + __expf(-g1[k])) * u1[k]);
  }
  ((short8v*)mlp)[i] = r;
}

// ---------------- RoPE cos/sin table: [T][32][2] f32 ----------------
__global__ __launch_bounds__(256)
void rope_table(const int* __restrict__ pos, float* __restrict__ tab) {
  int i = blockIdx.x * 256 + threadIdx.x;
  int t = i >> 5, ii = i & 31;
  float p = (float)pos[t];
  float freq = __expf(-(float)ii * (9.210340371976184f / 32.0f));
  float ang = p * freq;
  tab[2 * i]     = cosf(ang);
  tab[2 * i + 1] = sinf(ang);
}

// ---------------- V transpose: vbf [bkh][j][d] -> vtbf [bkh][d][j] ----------------
#define KPAD 68

__global__ __launch_bounds__(256)
void transpose_v(const short* __restrict__ vbf, short* __restrict__ vtbf) {
  __shared__ short sv[64 * KPAD];
  const int jt = blockIdx.x, kh = blockIdx.y, b = blockIdx.z;
  const int tid = threadIdx.x;
  const short* src = vbf + ((size_t)((b * HKV_ + kh) * S_ + jt * 64)) * HD_;
  #pragma unroll
  for (int it = 0; it < 2; it++) {
    int c = it * 256 + tid;
    int rr = c >> 3, ch = (c & 7) * 8;
    *(short8v*)(&sv[rr * KPAD + ch]) = *(const short8v*)(src + (size_t)rr * HD_ + ch);
  }
  __syncthreads();
  const int dc = tid >> 2;
  const int jc = (tid & 3) * 16;
  short8v o1, o2;
  #pragma unroll
  for (int k = 0; k < 8; k++) o1[k] = sv[(jc + k) * KPAD + dc];
  #pragma unroll
  for (int k = 0; k < 8; k++) o2[k] = sv[(jc + 8 + k) * KPAD + dc];
  short* od = vtbf + ((size_t)((b * HKV_ + kh) * HD_ + dc)) * S_ + jt * 64 + jc;
  *(short8v*)od       = o1;
  *(short8v*)(od + 8) = o2;
}

// ---------------- MFMA flash attention (bf16 out) ----------------
__global__ __launch_bounds__(256)
void attn_mfma(const short* __restrict__ qbf, const short* __restrict__ kbf,
               const short* __restrict__ vtbf, short* __restrict__ obf) {
  __shared__ short sK[64 * KPAD];
  __shared__ short sVt[64 * KPAD];
  __shared__ short sP[4][16 * KPAD];
  const int qb = blockIdx.x;
  const int h  = blockIdx.y;
  const int b  = blockIdx.z;
  const int kh = h >> 2;
  const int tid  = threadIdx.x;
  const int lane = tid & 63;
  const int wv   = tid >> 6;
  const int q0 = qb * 64;
  const int cc = lane & 15;
  const int g  = lane >> 4;

  short8v qf0, qf1;
  {
    const short* qrow = qbf + ((size_t)((b * HQ_ + h) * S_ + q0 + wv * 16 + cc)) * HD_;
    qf0 = *(const short8v*)(qrow + g * 8);
    qf1 = *(const short8v*)(qrow + g * 8 + 32);
  }
  float4v accO[4] = {};
  float m_r[4], l_r[4];
  #pragma unroll
  for (int r = 0; r < 4; r++) { m_r[r] = -1e30f; l_r[r] = 0.f; }

  const short* kb = kbf  + ((size_t)(b * HKV_ + kh)) * S_ * HD_;
  const short* vb = vtbf + ((size_t)(b * HKV_ + kh)) * HD_ * S_;

  for (int jt = 0; jt <= qb; jt++) {
    const int j0 = jt * 64;
    #pragma unroll
    for (int it = 0; it < 2; it++) {
      int idx = it * 256 + tid;
      int rr = idx >> 3, ch = (idx & 7) * 8;
      *(short8v*)(&sK[rr * KPAD + ch])  = *(const short8v*)(kb + (size_t)(j0 + rr) * HD_ + ch);
      *(short8v*)(&sVt[rr * KPAD + ch]) = *(const short8v*)(vb + (size_t)rr * S_ + j0 + ch);
    }
    __syncthreads();

    float4v sc[4] = {};
    #pragma unroll
    for (int ct = 0; ct < 4; ct++) {
      short8v k0 = *(const short8v*)(&sK[(ct * 16 + cc) * KPAD + g * 8]);
      short8v k1 = *(const short8v*)(&sK[(ct * 16 + cc) * KPAD + g * 8 + 32]);
      sc[ct] = __builtin_amdgcn_mfma_f32_16x16x32_bf16(qf0, k0, sc[ct], 0, 0, 0);
      sc[ct] = __builtin_amdgcn_mfma_f32_16x16x32_bf16(qf1, k1, sc[ct], 0, 0, 0);
    }
    if (jt == qb) {
      #pragma unroll
      for (int ct = 0; ct < 4; ct++)
        #pragma unroll
        for (int r = 0; r < 4; r++)
          if (j0 + ct * 16 + cc > q0 + wv * 16 + g * 4 + r) sc[ct][r] = -1e30f;
    }
    float corr[4];
    #pragma unroll
    for (int r = 0; r < 4; r++) {
      float pm = fmaxf(fmaxf(sc[0][r], sc[1][r]), fmaxf(sc[2][r], sc[3][r]));
      pm = fmaxf(pm, __shfl_xor(pm, 1, 64));
      pm = fmaxf(pm, __shfl_xor(pm, 2, 64));
      pm = fmaxf(pm, __shfl_xor(pm, 4, 64));
      pm = fmaxf(pm, __shfl_xor(pm, 8, 64));
      float mn = fmaxf(m_r[r], pm);
      corr[r] = __expf(m_r[r] - mn);
      m_r[r] = mn;
      float rs = 0.f;
      #pragma unroll
      for (int ct = 0; ct < 4; ct++) {
        float p = __expf(sc[ct][r] - mn);
        sc[ct][r] = p;
        rs += p;
      }
      rs += __shfl_xor(rs, 1, 64);
      rs += __shfl_xor(rs, 2, 64);
      rs += __shfl_xor(rs, 4, 64);
      rs += __shfl_xor(rs, 8, 64);
      l_r[r] = l_r[r] * corr[r] + rs;
    }
    #pragma unroll
    for (int ct = 0; ct < 4; ct++)
      #pragma unroll
      for (int r = 0; r < 4; r++)
        sP[wv][(g * 4 + r) * KPAD + ct * 16 + cc] = f2bf(sc[ct][r]);
    #pragma unroll
    for (int dt = 0; dt < 4; dt++)
      #pragma unroll
      for (int r = 0; r < 4; r++)
        accO[dt][r] *= corr[r];
    short8v pf0 = *(const short8v*)(&sP[wv][cc * KPAD + g * 8]);
    short8v pf1 = *(const short8v*)(&sP[wv][cc * KPAD + g * 8 + 32]);
    #pragma unroll
    for (int dt = 0; dt < 4; dt++) {
      short8v v0 = *(const short8v*)(&sVt[(dt * 16 + cc) * KPAD + g * 8]);
      short8v v1 = *(const short8v*)(&sVt[(dt * 16 + cc) * KPAD + g * 8 + 32]);
      accO[dt] = __builtin_amdgcn_mfma_f32_16x16x32_bf16(pf0, v0, accO[dt], 0, 0, 0);
      accO[dt] = __builtin_amdgcn_mfma_f32_16x16x32_bf16(pf1, v1, accO[dt], 0, 0, 0);
    }
    __syncthreads();
  }
  #pragma unroll
  for (int dt = 0; dt < 4; dt++)
    #pragma unroll
    for (int r = 0; r < 4; r++) {
      int q = q0 + wv * 16 + g * 4 + r;
      obf[((size_t)(b * S_ + q)) * 2048 + h * 64 + dt * 16 + cc] = f2bf(accO[dt][r] / l_r[r]);
    }
}

// ---------------- launch ----------------
extern "C" void kernel_launch(void* const* d_in, const int* in_sizes, int n_in,
                              void* d_out, int out_size, void* d_ws, size_t ws_size,
                              hipStream_t stream) {
  const int*   ids   = (const int*)d_in[0];
  const int*   pos   = (const int*)d_in[1];
  const float* embed = (const float*)d_in[2];
  const float* w_qkv = (const float*)d_in[3];
  const float* w_o   = (const float*)d_in[4];
  const float* w_gu  = (const float*)d_in[5];
  const float* w_dn  = (const float*)d_in[6];
  const float* ln1   = (const float*)d_in[7];
  const float* ln2   = (const float*)d_in[8];
  const float* normw = (const float*)d_in[9];
  float* out = (float*)d_out;

  char* p = (char*)d_ws;
  short* wT    = (short*)p; p += (size_t)11264 * 2048 * 2;
  float* h     = (float*)p; p += (size_t)T_ * D_ * 4;
  float* res   = (float*)p; p += (size_t)T_ * D_ * 4;
  short* hnbf  = (short*)p; p += (size_t)T_ * D_ * 2;
  short* obf   = (short*)p; p += (size_t)T_ * D_ * 2;
  short* mlpbf = (short*)p; p += (size_t)T_ * I_ * 2;
  float* tab   = (float*)p; p += (size_t)T_ * 64 * 4;
  short* qbf   = (short*)p; p += (size_t)B_ * HQ_ * S_ * HD_ * 2;
  short* kbf   = (short*)p; p += (size_t)B_ * HKV_ * S_ * HD_ * 2;
  short* vbf   = (short*)p; p += (size_t)B_ * HKV_ * S_ * HD_ * 2;
  short* vtbf  = (short*)p; p += (size_t)B_ * HKV_ * HD_ * S_ * 2;
  float* gu    = (float*)p; p += (size_t)T_ * 2 * I_ * 4;   // 92 MB f32

  embed_gather<<<T_ * D_ / 4 / 256, 256, 0, stream>>>(ids, embed, h);
  rope_table<<<T_ * 32 / 256, 256, 0, stream>>>(pos, tab);

  for (int l = 0; l < L_; l++) {
    rmsnorm_add<<<T_, 256, 0, stream>>>(h, res, ln1 + l * D_, hnbf, l == 0 ? 1 : 0, 1);

    transpose_bf16<<<dim3(3072 / 64, 2048 / 64), 256, 0, stream>>>(
        w_qkv + (size_t)l * 2048 * 3072, wT, 2048, 3072);
    gemm_qkv_rope<<<dim3(3072 / BN, T_ / BM), 256, 0, stream>>>(
        hnbf, wT, tab, qbf, kbf, vbf, 2048);

    transpose_v<<<dim3(16, 8, 2), 256, 0, stream>>>(vbf, vtbf);
    attn_mfma<<<dim3(16, 32, 2), 256, 0, stream>>>(qbf, kbf, vtbf, obf);

    transpose_bf16<<<dim3(2048 / 64, 2048 / 64), 256, 0, stream>>>(
        w_o + (size_t)l * 2048 * 2048, wT, 2048, 2048);
    gemm_n64<<<dim3(2048 / 64, T_ / BM), 256, 0, stream>>>(
        obf, wT, h, T_, 2048, 2048);

    rmsnorm_add<<<T_, 256, 0, stream>>>(h, res, ln2 + l * D_, hnbf, 0, 1);

    transpose_bf16<<<dim3(11264 / 64, 2048 / 64), 256, 0, stream>>>(
        w_gu + (size_t)l * 2048 * 11264, wT, 2048, 11264);
    gemm_big<<<dim3(11264 / 256, T_ / 128), 512, 0, stream>>>(
        hnbf, wT, gu, T_, 11264, 2048);

    swiglu_kernel<<<T_ * I_ / 8 / 256, 256, 0, stream>>>(gu, mlpbf);

    transpose_bf16<<<dim3(2048 / 64, 5632 / 64), 256, 0, stream>>>(
        w_dn + (size_t)l * 5632 * 2048, wT, 5632, 2048);
    gemm_n64<<<dim3(2048 / 64, T_ / BM), 256, 0, stream>>>(
        mlpbf, wT, h, T_, 2048, 5632);
  }
  rmsnorm_add<<<T_, 256, 0, stream>>>(h, res, normw, out, 0, 0);
}

// Round 8
// 1828.073 us; speedup vs baseline: 1.1033x; 1.1033x over previous
//
#include <hip/hip_runtime.h>
#include <hip/hip_bf16.h>

#define B_ 2
#define S_ 1024
#define T_ (B_*S_)
#define D_ 2048
#define L_ 4
#define HQ_ 32
#define HKV_ 8
#define HD_ 64
#define I_ 5632
#define EPS_ 1e-5f
#define SCALE_ 0.125f

typedef __attribute__((ext_vector_type(4))) float  float4v;
typedef __attribute__((ext_vector_type(8))) short  short8v;

#define GLOAD16(g, l) \
  __builtin_amdgcn_global_load_lds((const __attribute__((address_space(1))) void*)(g), \
                                   (__attribute__((address_space(3))) void*)(l), 16, 0, 0)

__device__ __forceinline__ short f2bf(float f) {
  union { float f; unsigned u; } c; c.f = f;
  unsigned u = c.u + 0x7fffu + ((c.u >> 16) & 1u);
  return (short)(u >> 16);
}

// bijective XCD-aware block swizzle (m204), column-major decode
__device__ __forceinline__ void xcd_swizzle(int gx, int gy, int& bx, int& by) {
  int nwg = gx * gy;
  int orig = by * gx + bx;
  int q = nwg >> 3, r = nwg & 7;
  int xcd = orig & 7, loc = orig >> 3;
  int swz = (xcd < r ? xcd * (q + 1) : r * (q + 1) + (xcd - r) * q) + loc;
  bx = swz / gy;
  by = swz - bx * gy;
}

// ---------------- transpose f32 [K][N] -> bf16 [N][K], 64x64 vectorized ----------------
__global__ __launch_bounds__(256)
void transpose_bf16(const float* __restrict__ in, short* __restrict__ out,
                    int K, int N) {
  __shared__ float t[64][65];
  const int bx = blockIdx.x * 64;   // N
  const int by = blockIdx.y * 64;   // K
  const int tid = threadIdx.x;
  const int lr = tid >> 4;
  const int lc = (tid & 15) * 4;
  #pragma unroll
  for (int j = 0; j < 64; j += 16) {
    float4v v = *(const float4v*)(in + (size_t)(by + lr + j) * N + bx + lc);
    t[lr + j][lc] = v[0]; t[lr + j][lc + 1] = v[1];
    t[lr + j][lc + 2] = v[2]; t[lr + j][lc + 3] = v[3];
  }
  __syncthreads();
  const int nr = tid >> 3;
  const int kc = (tid & 7) * 8;
  #pragma unroll
  for (int j = 0; j < 64; j += 32) {
    short8v y;
    #pragma unroll
    for (int e = 0; e < 8; e++) y[e] = f2bf(t[kc + e][nr + j]);
    *(short8v*)(out + (size_t)(bx + nr + j) * K + by + kc) = y;
  }
}

// ---------------- embedding gather ----------------
__global__ __launch_bounds__(256)
void embed_gather(const int* __restrict__ ids, const float* __restrict__ embed,
                  float* __restrict__ h) {
  size_t i = (size_t)blockIdx.x * 256 + threadIdx.x;
  int t  = (int)(i >> 9);
  int d4 = (int)(i & 511);
  ((float4v*)h)[i] = ((const float4v*)(embed + (size_t)ids[t] * D_))[d4];
}

// ---------------- fused residual-add + RMSNorm (bf16 or f32 out) ----------------
__global__ __launch_bounds__(256)
void rmsnorm_add(const float* __restrict__ x, float* __restrict__ res,
                 const float* __restrict__ w, void* __restrict__ outp,
                 int first, int bf16out) {
  const int row = blockIdx.x;
  const int tid = threadIdx.x;
  const size_t base = (size_t)row * D_;
  float4v v0 = ((const float4v*)(x + base))[tid * 2];
  float4v v1 = ((const float4v*)(x + base))[tid * 2 + 1];
  if (!first) {
    v0 += ((const float4v*)(res + base))[tid * 2];
    v1 += ((const float4v*)(res + base))[tid * 2 + 1];
  }
  ((float4v*)(res + base))[tid * 2]     = v0;
  ((float4v*)(res + base))[tid * 2 + 1] = v1;
  float ss = v0[0]*v0[0] + v0[1]*v0[1] + v0[2]*v0[2] + v0[3]*v0[3]
           + v1[0]*v1[0] + v1[1]*v1[1] + v1[2]*v1[2] + v1[3]*v1[3];
  #pragma unroll
  for (int off = 32; off > 0; off >>= 1) ss += __shfl_xor(ss, off, 64);
  __shared__ float red[4];
  if ((tid & 63) == 0) red[tid >> 6] = ss;
  __syncthreads();
  float tot = red[0] + red[1] + red[2] + red[3];
  float rs = rsqrtf(tot * (1.0f / D_) + EPS_);
  float4v w0 = ((const float4v*)w)[tid * 2];
  float4v w1 = ((const float4v*)w)[tid * 2 + 1];
  float4v o0 = v0 * rs * w0;
  float4v o1 = v1 * rs * w1;
  if (bf16out) {
    short8v y;
    #pragma unroll
    for (int k = 0; k < 4; k++) { y[k] = f2bf(o0[k]); y[k + 4] = f2bf(o1[k]); }
    ((short8v*)((char*)outp + base * 2))[tid] = y;
  } else {
    float* op = (float*)outp + base;
    ((float4v*)op)[tid * 2]     = o0;
    ((float4v*)op)[tid * 2 + 1] = o1;
  }
}

#define BM 128
#define BN 128
#define BKS 32

// ======== 128x128 8-wave GEMM, counted vmcnt(4) + T2 swizzle + setprio ========
// Same schedule as the verified gemm_big (r7), BN=128.  LDS 64KB dbuf ->
// 2 blocks/CU.  Wave tile 64x32 (2M x 4N waves).
__global__ __launch_bounds__(512, 4)
void gemm_big128(const short* __restrict__ A, const short* __restrict__ Bt,
                 float* __restrict__ C, int M, int N, int K) {
  __shared__ short sA[2][128 * 64];
  __shared__ short sB[2][128 * 64];
  int bx = blockIdx.x, by = blockIdx.y;
  xcd_swizzle(gridDim.x, gridDim.y, bx, by);
  const int tid  = threadIdx.x;
  const int lane = tid & 63;
  const int wv   = tid >> 6;
  const int wr   = wv >> 2;          // 0..1
  const int wc   = wv & 3;           // 0..3
  const int row0 = by * 128;
  const int col0 = bx * 128;
  const int fr = lane & 15;
  const int g  = lane >> 4;
  const int NT = K >> 6;

  float4v acc[4][2] = {};            // 32 VGPR

  int rS[2], cS[2];
  #pragma unroll
  for (int k = 0; k < 2; k++) {
    int s = tid + k * 512;
    rS[k] = s >> 3;
    cS[k] = (((s & 7) ^ (rS[k] & 7)) << 3);   // pre-swizzled source col
  }

#define STAGE128(t, buf) do { \
    int k0_ = (t) << 6; \
    _Pragma("unroll") \
    for (int k_ = 0; k_ < 2; k_++) \
      GLOAD16(A  + (size_t)(row0 + rS[k_]) * K + k0_ + cS[k_], \
              &sA[buf][(tid + k_ * 512) * 8]); \
    _Pragma("unroll") \
    for (int k_ = 0; k_ < 2; k_++) \
      GLOAD16(Bt + (size_t)(col0 + rS[k_]) * K + k0_ + cS[k_], \
              &sB[buf][(tid + k_ * 512) * 8]); \
  } while (0)

  STAGE128(0, 0);

  for (int t = 0; t < NT; t++) {
    const int cur = t & 1;
    if (t + 1 < NT) {
      STAGE128(t + 1, cur ^ 1);
      asm volatile("s_waitcnt vmcnt(4)" ::: "memory");
    } else {
      asm volatile("s_waitcnt vmcnt(0)" ::: "memory");
    }
    __builtin_amdgcn_s_barrier();
    __builtin_amdgcn_sched_barrier(0);

    const short* pA = &sA[cur][(wr * 64) * 64];
    const short* pB = &sB[cur][(wc * 32) * 64];
    #pragma unroll
    for (int ks = 0; ks < 2; ks++) {
      const int fswk = ((((ks << 2) | g) ^ (fr & 7)) << 3);
      short8v bfr[2], afr[4];
      #pragma unroll
      for (int ni = 0; ni < 2; ni++)
        bfr[ni] = *(const short8v*)(pB + (ni * 16 + fr) * 64 + fswk);
      #pragma unroll
      for (int m4 = 0; m4 < 4; m4++)
        afr[m4] = *(const short8v*)(pA + (m4 * 16 + fr) * 64 + fswk);
      __builtin_amdgcn_s_setprio(1);
      #pragma unroll
      for (int m4 = 0; m4 < 4; m4++)
        #pragma unroll
        for (int ni = 0; ni < 2; ni++)
          acc[m4][ni] = __builtin_amdgcn_mfma_f32_16x16x32_bf16(
              afr[m4], bfr[ni], acc[m4][ni], 0, 0, 0);
      __builtin_amdgcn_s_setprio(0);
    }
    asm volatile("" ::: "memory");
    __builtin_amdgcn_s_barrier();
  }

  #pragma unroll
  for (int m4 = 0; m4 < 4; m4++)
    #pragma unroll
    for (int ni = 0; ni < 2; ni++) {
      size_t base = (size_t)(row0 + wr * 64 + m4 * 16 + g * 4) * N
                    + col0 + wc * 32 + ni * 16 + fr;
      #pragma unroll
      for (int r = 0; r < 4; r++)
        C[base + (size_t)r * N] = acc[m4][ni][r];
    }
#undef STAGE128
}

// ======== gate_up GEMM + fused SwiGLU on the same schedule, vmcnt(6) ========
// gate cols [col0,col0+128), up rows at Bt[col0+I_ ...).  LDS 96KB dbuf.
__global__ __launch_bounds__(512, 2)
void gemm_glu_big(const short* __restrict__ A, const short* __restrict__ Bt,
                  short* __restrict__ mlp, int K) {
  __shared__ short sA[2][128 * 64];
  __shared__ short sG[2][128 * 64];
  __shared__ short sU[2][128 * 64];
  int bx = blockIdx.x, by = blockIdx.y;
  xcd_swizzle(gridDim.x, gridDim.y, bx, by);
  const int tid  = threadIdx.x;
  const int lane = tid & 63;
  const int wv   = tid >> 6;
  const int wr   = wv >> 2;
  const int wc   = wv & 3;
  const int row0 = by * 128;
  const int col0 = bx * 128;
  const int fr = lane & 15;
  const int g  = lane >> 4;
  const int NT = K >> 6;

  float4v accg[4][2] = {};
  float4v accu[4][2] = {};

  int rS[2], cS[2];
  #pragma unroll
  for (int k = 0; k < 2; k++) {
    int s = tid + k * 512;
    rS[k] = s >> 3;
    cS[k] = (((s & 7) ^ (rS[k] & 7)) << 3);
  }

#define STAGEGLU(t, buf) do { \
    int k0_ = (t) << 6; \
    _Pragma("unroll") \
    for (int k_ = 0; k_ < 2; k_++) \
      GLOAD16(A  + (size_t)(row0 + rS[k_]) * K + k0_ + cS[k_], \
              &sA[buf][(tid + k_ * 512) * 8]); \
    _Pragma("unroll") \
    for (int k_ = 0; k_ < 2; k_++) \
      GLOAD16(Bt + (size_t)(col0 + rS[k_]) * K + k0_ + cS[k_], \
              &sG[buf][(tid + k_ * 512) * 8]); \
    _Pragma("unroll") \
    for (int k_ = 0; k_ < 2; k_++) \
      GLOAD16(Bt + (size_t)(col0 + I_ + rS[k_]) * K + k0_ + cS[k_], \
              &sU[buf][(tid + k_ * 512) * 8]); \
  } while (0)

  STAGEGLU(0, 0);

  for (int t = 0; t < NT; t++) {
    const int cur = t & 1;
    if (t + 1 < NT) {
      STAGEGLU(t + 1, cur ^ 1);
      asm volatile("s_waitcnt vmcnt(6)" ::: "memory");
    } else {
      asm volatile("s_waitcnt vmcnt(0)" ::: "memory");
    }
    __builtin_amdgcn_s_barrier();
    __builtin_amdgcn_sched_barrier(0);

    const short* pA = &sA[cur][(wr * 64) * 64];
    const short* pG = &sG[cur][(wc * 32) * 64];
    const short* pU = &sU[cur][(wc * 32) * 64];
    #pragma unroll
    for (int ks = 0; ks < 2; ks++) {
      const int fswk = ((((ks << 2) | g) ^ (fr & 7)) << 3);
      short8v bg[2], bu[2], afr[4];
      #pragma unroll
      for (int ni = 0; ni < 2; ni++) {
        bg[ni] = *(const short8v*)(pG + (ni * 16 + fr) * 64 + fswk);
        bu[ni] = *(const short8v*)(pU + (ni * 16 + fr) * 64 + fswk);
      }
      #pragma unroll
      for (int m4 = 0; m4 < 4; m4++)
        afr[m4] = *(const short8v*)(pA + (m4 * 16 + fr) * 64 + fswk);
      __builtin_amdgcn_s_setprio(1);
      #pragma unroll
      for (int m4 = 0; m4 < 4; m4++)
        #pragma unroll
        for (int ni = 0; ni < 2; ni++) {
          accg[m4][ni] = __builtin_amdgcn_mfma_f32_16x16x32_bf16(
              afr[m4], bg[ni], accg[m4][ni], 0, 0, 0);
          accu[m4][ni] = __builtin_amdgcn_mfma_f32_16x16x32_bf16(
              afr[m4], bu[ni], accu[m4][ni], 0, 0, 0);
        }
      __builtin_amdgcn_s_setprio(0);
    }
    asm volatile("" ::: "memory");
    __builtin_amdgcn_s_barrier();
  }

  #pragma unroll
  for (int m4 = 0; m4 < 4; m4++)
    #pragma unroll
    for (int ni = 0; ni < 2; ni++) {
      size_t base = (size_t)(row0 + wr * 64 + m4 * 16 + g * 4) * I_
                    + col0 + wc * 32 + ni * 16 + fr;
      #pragma unroll
      for (int r = 0; r < 4; r++) {
        float gv = accg[m4][ni][r], uv = accu[m4][ni][r];
        mlp[base + (size_t)r * I_] = f2bf(gv / (1.0f + __expf(-gv)) * uv);
      }
    }
#undef STAGEGLU
}

// ------- QKV GEMM with fused RoPE epilogue (128x128 2-phase, proven) -------
__global__ __launch_bounds__(256)
void gemm_qkv_rope(const short* __restrict__ A, const short* __restrict__ Bt,
                   const float* __restrict__ tab, short* __restrict__ qbf,
                   short* __restrict__ kbf, short* __restrict__ vbf, int K) {
  __shared__ short sA[BM * BKS];
  __shared__ short sB[BN * BKS];
  int bx = blockIdx.x, by = blockIdx.y;
  xcd_swizzle(gridDim.x, gridDim.y, bx, by);
  const int tid  = threadIdx.x;
  const int lane = tid & 63;
  const int wave = tid >> 6;
  const int wm = (wave >> 1) << 6;
  const int wn = (wave & 1) << 6;
  const int row0 = by * BM;
  const int col0 = bx * BN;
  const int fr = lane & 15;
  const int fk = (lane >> 4) << 3;
  float4v acc[4][4] = {};

  const int r_st  = tid >> 2;
  const int kc_st = (tid & 3) << 3;
  const short* pA = A  + (size_t)(row0 + r_st) * K + kc_st;
  const short* pB = Bt + (size_t)(col0 + r_st) * K + kc_st;
  const size_t stride64 = (size_t)64 * K;
  short* lA0 = &sA[tid * 8];
  short* lA1 = &sA[(256 + tid) * 8];
  short* lB0 = &sB[tid * 8];
  short* lB1 = &sB[(256 + tid) * 8];

  for (int k0 = 0; k0 < K; k0 += BKS) {
    GLOAD16(pA, lA0);
    GLOAD16(pA + stride64, lA1);
    GLOAD16(pB, lB0);
    GLOAD16(pB + stride64, lB1);
    pA += BKS; pB += BKS;
    __syncthreads();
    short8v af[4], bfr[4];
    #pragma unroll
    for (int f = 0; f < 4; f++) {
      af[f]  = *(const short8v*)(&sA[(wm + f * 16 + fr) * BKS + fk]);
      bfr[f] = *(const short8v*)(&sB[(wn + f * 16 + fr) * BKS + fk]);
    }
    #pragma unroll
    for (int i = 0; i < 4; i++)
      #pragma unroll
      for (int j = 0; j < 4; j++)
        acc[i][j] = __builtin_amdgcn_mfma_f32_16x16x32_bf16(af[i], bfr[j], acc[i][j], 0, 0, 0);
    __syncthreads();
  }
  const int cr = (lane >> 4) << 2;
  const int cc = lane & 15;
  const int head = (col0 + wn) >> 6;

  if (head < HQ_ + HKV_) {
    const float sc = (head < HQ_) ? SCALE_ : 1.0f;
    #pragma unroll
    for (int i = 0; i < 4; i++)
      #pragma unroll
      for (int jj = 0; jj < 2; jj++)
        #pragma unroll
        for (int r = 0; r < 4; r++) {
          int m = row0 + wm + i * 16 + cr + r;
          int b = m >> 10, s = m & (S_ - 1);
          int d1 = jj * 16 + cc;
          float x1 = acc[i][jj][r], x2 = acc[i][jj + 2][r];
          const float* tb = tab + (size_t)m * 64 + d1 * 2;
          float c = tb[0], sn = tb[1];
          short y1 = f2bf((x1 * c - x2 * sn) * sc);
          short y2 = f2bf((x2 * c + x1 * sn) * sc);
          size_t base;
          if (head < HQ_)
            base = ((size_t)((b * HQ_ + head) * S_ + s)) * HD_;
          else
            base = ((size_t)((b * HKV_ + head - HQ_) * S_ + s)) * HD_;
          short* dst = (head < HQ_) ? qbf : kbf;
          dst[base + d1]      = y1;
          dst[base + d1 + 32] = y2;
        }
  } else {
    const int vh = head - HQ_ - HKV_;
    #pragma unroll
    for (int i = 0; i < 4; i++)
      #pragma unroll
      for (int j = 0; j < 4; j++)
        #pragma unroll
        for (int r = 0; r < 4; r++) {
          int m = row0 + wm + i * 16 + cr + r;
          int b = m >> 10, s = m & (S_ - 1);
          vbf[((size_t)((b * HKV_ + vh) * S_ + s)) * HD_ + j * 16 + cc] =
              f2bf(acc[i][j][r]);
        }
  }
}

// ---------------- RoPE cos/sin table: [T][32][2] f32 ----------------
__global__ __launch_bounds__(256)
void rope_table(const int* __restrict__ pos, float* __restrict__ tab) {
  int i = blockIdx.x * 256 + threadIdx.x;
  int t = i >> 5, ii = i & 31;
  float p = (float)pos[t];
  float freq = __expf(-(float)ii * (9.210340371976184f / 32.0f));
  float ang = p * freq;
  tab[2 * i]     = cosf(ang);
  tab[2 * i + 1] = sinf(ang);
}

// ---------------- V transpose: vbf [bkh][j][d] -> vtbf [bkh][d][j] ----------------
#define KPAD 68

__global__ __launch_bounds__(256)
void transpose_v(const short* __restrict__ vbf, short* __restrict__ vtbf) {
  __shared__ short sv[64 * KPAD];
  const int jt = blockIdx.x, kh = blockIdx.y, b = blockIdx.z;
  const int tid = threadIdx.x;
  const short* src = vbf + ((size_t)((b * HKV_ + kh) * S_ + jt * 64)) * HD_;
  #pragma unroll
  for (int it = 0; it < 2; it++) {
    int c = it * 256 + tid;
    int rr = c >> 3, ch = (c & 7) * 8;
    *(short8v*)(&sv[rr * KPAD + ch]) = *(const short8v*)(src + (size_t)rr * HD_ + ch);
  }
  __syncthreads();
  const int dc = tid >> 2;
  const int jc = (tid & 3) * 16;
  short8v o1, o2;
  #pragma unroll
  for (int k = 0; k < 8; k++) o1[k] = sv[(jc + k) * KPAD + dc];
  #pragma unroll
  for (int k = 0; k < 8; k++) o2[k] = sv[(jc + 8 + k) * KPAD + dc];
  short* od = vtbf + ((size_t)((b * HKV_ + kh) * HD_ + dc)) * S_ + jt * 64 + jc;
  *(short8v*)od       = o1;
  *(short8v*)(od + 8) = o2;
}

// ---------------- MFMA flash attention (bf16 out) ----------------
__global__ __launch_bounds__(256)
void attn_mfma(const short* __restrict__ qbf, const short* __restrict__ kbf,
               const short* __restrict__ vtbf, short* __restrict__ obf) {
  __shared__ short sK[64 * KPAD];
  __shared__ short sVt[64 * KPAD];
  __shared__ short sP[4][16 * KPAD];
  const int qb = blockIdx.x;
  const int h  = blockIdx.y;
  const int b  = blockIdx.z;
  const int kh = h >> 2;
  const int tid  = threadIdx.x;
  const int lane = tid & 63;
  const int wv   = tid >> 6;
  const int q0 = qb * 64;
  const int cc = lane & 15;
  const int g  = lane >> 4;

  short8v qf0, qf1;
  {
    const short* qrow = qbf + ((size_t)((b * HQ_ + h) * S_ + q0 + wv * 16 + cc)) * HD_;
    qf0 = *(const short8v*)(qrow + g * 8);
    qf1 = *(const short8v*)(qrow + g * 8 + 32);
  }
  float4v accO[4] = {};
  float m_r[4], l_r[4];
  #pragma unroll
  for (int r = 0; r < 4; r++) { m_r[r] = -1e30f; l_r[r] = 0.f; }

  const short* kb = kbf  + ((size_t)(b * HKV_ + kh)) * S_ * HD_;
  const short* vb = vtbf + ((size_t)(b * HKV_ + kh)) * HD_ * S_;

  for (int jt = 0; jt <= qb; jt++) {
    const int j0 = jt * 64;
    #pragma unroll
    for (int it = 0; it < 2; it++) {
      int idx = it * 256 + tid;
      int rr = idx >> 3, ch = (idx & 7) * 8;
      *(short8v*)(&sK[rr * KPAD + ch])  = *(const short8v*)(kb + (size_t)(j0 + rr) * HD_ + ch);
      *(short8v*)(&sVt[rr * KPAD + ch]) = *(const short8v*)(vb + (size_t)rr * S_ + j0 + ch);
    }
    __syncthreads();

    float4v sc[4] = {};
    #pragma unroll
    for (int ct = 0; ct < 4; ct++) {
      short8v k0 = *(const short8v*)(&sK[(ct * 16 + cc) * KPAD + g * 8]);
      short8v k1 = *(const short8v*)(&sK[(ct * 16 + cc) * KPAD + g * 8 + 32]);
      sc[ct] = __builtin_amdgcn_mfma_f32_16x16x32_bf16(qf0, k0, sc[ct], 0, 0, 0);
      sc[ct] = __builtin_amdgcn_mfma_f32_16x16x32_bf16(qf1, k1, sc[ct], 0, 0, 0);
    }
    if (jt == qb) {
      #pragma unroll
      for (int ct = 0; ct < 4; ct++)
        #pragma unroll
        for (int r = 0; r < 4; r++)
          if (j0 + ct * 16 + cc > q0 + wv * 16 + g * 4 + r) sc[ct][r] = -1e30f;
    }
    float corr[4];
    #pragma unroll
    for (int r = 0; r < 4; r++) {
      float pm = fmaxf(fmaxf(sc[0][r], sc[1][r]), fmaxf(sc[2][r], sc[3][r]));
      pm = fmaxf(pm, __shfl_xor(pm, 1, 64));
      pm = fmaxf(pm, __shfl_xor(pm, 2, 64));
      pm = fmaxf(pm, __shfl_xor(pm, 4, 64));
      pm = fmaxf(pm, __shfl_xor(pm, 8, 64));
      float mn = fmaxf(m_r[r], pm);
      corr[r] = __expf(m_r[r] - mn);
      m_r[r] = mn;
      float rs = 0.f;
      #pragma unroll
      for (int ct = 0; ct < 4; ct++) {
        float p = __expf(sc[ct][r] - mn);
        sc[ct][r] = p;
        rs += p;
      }
      rs += __shfl_xor(rs, 1, 64);
      rs += __shfl_xor(rs, 2, 64);
      rs += __shfl_xor(rs, 4, 64);
      rs += __shfl_xor(rs, 8, 64);
      l_r[r] = l_r[r] * corr[r] + rs;
    }
    #pragma unroll
    for (int ct = 0; ct < 4; ct++)
      #pragma unroll
      for (int r = 0; r < 4; r++)
        sP[wv][(g * 4 + r) * KPAD + ct * 16 + cc] = f2bf(sc[ct][r]);
    #pragma unroll
    for (int dt = 0; dt < 4; dt++)
      #pragma unroll
      for (int r = 0; r < 4; r++)
        accO[dt][r] *= corr[r];
    short8v pf0 = *(const short8v*)(&sP[wv][cc * KPAD + g * 8]);
    short8v pf1 = *(const short8v*)(&sP[wv][cc * KPAD + g * 8 + 32]);
    #pragma unroll
    for (int dt = 0; dt < 4; dt++) {
      short8v v0 = *(const short8v*)(&sVt[(dt * 16 + cc) * KPAD + g * 8]);
      short8v v1 = *(const short8v*)(&sVt[(dt * 16 + cc) * KPAD + g * 8 + 32]);
      accO[dt] = __builtin_amdgcn_mfma_f32_16x16x32_bf16(pf0, v0, accO[dt], 0, 0, 0);
      accO[dt] = __builtin_amdgcn_mfma_f32_16x16x32_bf16(pf1, v1, accO[dt], 0, 0, 0);
    }
    __syncthreads();
  }
  #pragma unroll
  for (int dt = 0; dt < 4; dt++)
    #pragma unroll
    for (int r = 0; r < 4; r++) {
      int q = q0 + wv * 16 + g * 4 + r;
      obf[((size_t)(b * S_ + q)) * 2048 + h * 64 + dt * 16 + cc] = f2bf(accO[dt][r] / l_r[r]);
    }
}

// ---------------- launch ----------------
extern "C" void kernel_launch(void* const* d_in, const int* in_sizes, int n_in,
                              void* d_out, int out_size, void* d_ws, size_t ws_size,
                              hipStream_t stream) {
  const int*   ids   = (const int*)d_in[0];
  const int*   pos   = (const int*)d_in[1];
  const float* embed = (const float*)d_in[2];
  const float* w_qkv = (const float*)d_in[3];
  const float* w_o   = (const float*)d_in[4];
  const float* w_gu  = (const float*)d_in[5];
  const float* w_dn  = (const float*)d_in[6];
  const float* ln1   = (const float*)d_in[7];
  const float* ln2   = (const float*)d_in[8];
  const float* normw = (const float*)d_in[9];
  float* out = (float*)d_out;

  char* p = (char*)d_ws;
  short* wT    = (short*)p; p += (size_t)11264 * 2048 * 2;
  float* h     = (float*)p; p += (size_t)T_ * D_ * 4;
  float* res   = (float*)p; p += (size_t)T_ * D_ * 4;
  short* hnbf  = (short*)p; p += (size_t)T_ * D_ * 2;
  short* obf   = (short*)p; p += (size_t)T_ * D_ * 2;
  short* mlpbf = (short*)p; p += (size_t)T_ * I_ * 2;
  float* tab   = (float*)p; p += (size_t)T_ * 64 * 4;
  short* qbf   = (short*)p; p += (size_t)B_ * HQ_ * S_ * HD_ * 2;
  short* kbf   = (short*)p; p += (size_t)B_ * HKV_ * S_ * HD_ * 2;
  short* vbf   = (short*)p; p += (size_t)B_ * HKV_ * S_ * HD_ * 2;
  short* vtbf  = (short*)p; p += (size_t)B_ * HKV_ * HD_ * S_ * 2;

  embed_gather<<<T_ * D_ / 4 / 256, 256, 0, stream>>>(ids, embed, h);
  rope_table<<<T_ * 32 / 256, 256, 0, stream>>>(pos, tab);

  for (int l = 0; l < L_; l++) {
    rmsnorm_add<<<T_, 256, 0, stream>>>(h, res, ln1 + l * D_, hnbf, l == 0 ? 1 : 0, 1);

    transpose_bf16<<<dim3(3072 / 64, 2048 / 64), 256, 0, stream>>>(
        w_qkv + (size_t)l * 2048 * 3072, wT, 2048, 3072);
    gemm_qkv_rope<<<dim3(3072 / BN, T_ / BM), 256, 0, stream>>>(
        hnbf, wT, tab, qbf, kbf, vbf, 2048);

    transpose_v<<<dim3(16, 8, 2), 256, 0, stream>>>(vbf, vtbf);
    attn_mfma<<<dim3(16, 32, 2), 256, 0, stream>>>(qbf, kbf, vtbf, obf);

    transpose_bf16<<<dim3(2048 / 64, 2048 / 64), 256, 0, stream>>>(
        w_o + (size_t)l * 2048 * 2048, wT, 2048, 2048);
    gemm_big128<<<dim3(2048 / 128, T_ / 128), 512, 0, stream>>>(
        obf, wT, h, T_, 2048, 2048);

    rmsnorm_add<<<T_, 256, 0, stream>>>(h, res, ln2 + l * D_, hnbf, 0, 1);

    transpose_bf16<<<dim3(11264 / 64, 2048 / 64), 256, 0, stream>>>(
        w_gu + (size_t)l * 2048 * 11264, wT, 2048, 11264);
    gemm_glu_big<<<dim3(I_ / 128, T_ / 128), 512, 0, stream>>>(
        hnbf, wT, mlpbf, 2048);

    transpose_bf16<<<dim3(2048 / 64, 5632 / 64), 256, 0, stream>>>(
        w_dn + (size_t)l * 5632 * 2048, wT, 5632, 2048);
    gemm_big128<<<dim3(2048 / 128, T_ / 128), 512, 0, stream>>>(
        mlpbf, wT, h, T_, 2048, 5632);
  }
  rmsnorm_add<<<T_, 256, 0, stream>>>(h, res, normw, out, 0, 0);
}

// Round 9
// 1766.445 us; speedup vs baseline: 1.1418x; 1.0349x over previous
//
#include <hip/hip_runtime.h>
#include <hip/hip_bf16.h>

#define B_ 2
#define S_ 1024
#define T_ (B_*S_)
#define D_ 2048
#define L_ 4
#define HQ_ 32
#define HKV_ 8
#define HD_ 64
#define I_ 5632
#define EPS_ 1e-5f
#define SCALE_ 0.125f

typedef __attribute__((ext_vector_type(4))) float  float4v;
typedef __attribute__((ext_vector_type(8))) short  short8v;

#define GLOAD16(g, l) \
  __builtin_amdgcn_global_load_lds((const __attribute__((address_space(1))) void*)(g), \
                                   (__attribute__((address_space(3))) void*)(l), 16, 0, 0)

__device__ __forceinline__ short f2bf(float f) {
  union { float f; unsigned u; } c; c.f = f;
  unsigned u = c.u + 0x7fffu + ((c.u >> 16) & 1u);
  return (short)(u >> 16);
}

// bijective XCD-aware block swizzle (m204), column-major decode
__device__ __forceinline__ void xcd_swizzle(int gx, int gy, int& bx, int& by) {
  int nwg = gx * gy;
  int orig = by * gx + bx;
  int q = nwg >> 3, r = nwg & 7;
  int xcd = orig & 7, loc = orig >> 3;
  int swz = (xcd < r ? xcd * (q + 1) : r * (q + 1) + (xcd - r) * q) + loc;
  bx = swz / gy;
  by = swz - bx * gy;
}

// ---------------- transpose f32 [K][N] -> bf16 [N][K], 64x64 vectorized ----------------
__global__ __launch_bounds__(256)
void transpose_bf16(const float* __restrict__ in, short* __restrict__ out,
                    int K, int N) {
  __shared__ float t[64][65];
  const int bx = blockIdx.x * 64;   // N
  const int by = blockIdx.y * 64;   // K
  const int tid = threadIdx.x;
  const int lr = tid >> 4;
  const int lc = (tid & 15) * 4;
  #pragma unroll
  for (int j = 0; j < 64; j += 16) {
    float4v v = *(const float4v*)(in + (size_t)(by + lr + j) * N + bx + lc);
    t[lr + j][lc] = v[0]; t[lr + j][lc + 1] = v[1];
    t[lr + j][lc + 2] = v[2]; t[lr + j][lc + 3] = v[3];
  }
  __syncthreads();
  const int nr = tid >> 3;
  const int kc = (tid & 7) * 8;
  #pragma unroll
  for (int j = 0; j < 64; j += 32) {
    short8v y;
    #pragma unroll
    for (int e = 0; e < 8; e++) y[e] = f2bf(t[kc + e][nr + j]);
    *(short8v*)(out + (size_t)(bx + nr + j) * K + by + kc) = y;
  }
}

// ---------------- embedding gather ----------------
__global__ __launch_bounds__(256)
void embed_gather(const int* __restrict__ ids, const float* __restrict__ embed,
                  float* __restrict__ h) {
  size_t i = (size_t)blockIdx.x * 256 + threadIdx.x;
  int t  = (int)(i >> 9);
  int d4 = (int)(i & 511);
  ((float4v*)h)[i] = ((const float4v*)(embed + (size_t)ids[t] * D_))[d4];
}

// ---------------- fused residual-add + RMSNorm (bf16 or f32 out) ----------------
__global__ __launch_bounds__(256)
void rmsnorm_add(const float* __restrict__ x, float* __restrict__ res,
                 const float* __restrict__ w, void* __restrict__ outp,
                 int first, int bf16out) {
  const int row = blockIdx.x;
  const int tid = threadIdx.x;
  const size_t base = (size_t)row * D_;
  float4v v0 = ((const float4v*)(x + base))[tid * 2];
  float4v v1 = ((const float4v*)(x + base))[tid * 2 + 1];
  if (!first) {
    v0 += ((const float4v*)(res + base))[tid * 2];
    v1 += ((const float4v*)(res + base))[tid * 2 + 1];
  }
  ((float4v*)(res + base))[tid * 2]     = v0;
  ((float4v*)(res + base))[tid * 2 + 1] = v1;
  float ss = v0[0]*v0[0] + v0[1]*v0[1] + v0[2]*v0[2] + v0[3]*v0[3]
           + v1[0]*v1[0] + v1[1]*v1[1] + v1[2]*v1[2] + v1[3]*v1[3];
  #pragma unroll
  for (int off = 32; off > 0; off >>= 1) ss += __shfl_xor(ss, off, 64);
  __shared__ float red[4];
  if ((tid & 63) == 0) red[tid >> 6] = ss;
  __syncthreads();
  float tot = red[0] + red[1] + red[2] + red[3];
  float rs = rsqrtf(tot * (1.0f / D_) + EPS_);
  float4v w0 = ((const float4v*)w)[tid * 2];
  float4v w1 = ((const float4v*)w)[tid * 2 + 1];
  float4v o0 = v0 * rs * w0;
  float4v o1 = v1 * rs * w1;
  if (bf16out) {
    short8v y;
    #pragma unroll
    for (int k = 0; k < 4; k++) { y[k] = f2bf(o0[k]); y[k + 4] = f2bf(o1[k]); }
    ((short8v*)((char*)outp + base * 2))[tid] = y;
  } else {
    float* op = (float*)outp + base;
    ((float4v*)op)[tid * 2]     = o0;
    ((float4v*)op)[tid * 2 + 1] = o1;
  }
}

// ======== 128x128 8-wave GEMM, counted vmcnt(4) + T2 swizzle + setprio ========
// LDS 64KB dbuf -> 2 blocks/CU.  Wave tile 64x32 (2M x 4N waves).
__global__ __launch_bounds__(512, 4)
void gemm_big128(const short* __restrict__ A, const short* __restrict__ Bt,
                 float* __restrict__ C, int M, int N, int K) {
  __shared__ short sA[2][128 * 64];
  __shared__ short sB[2][128 * 64];
  int bx = blockIdx.x, by = blockIdx.y;
  xcd_swizzle(gridDim.x, gridDim.y, bx, by);
  const int tid  = threadIdx.x;
  const int lane = tid & 63;
  const int wv   = tid >> 6;
  const int wr   = wv >> 2;          // 0..1
  const int wc   = wv & 3;           // 0..3
  const int row0 = by * 128;
  const int col0 = bx * 128;
  const int fr = lane & 15;
  const int g  = lane >> 4;
  const int NT = K >> 6;

  float4v acc[4][2] = {};            // 32 VGPR

  int rS[2], cS[2];
  #pragma unroll
  for (int k = 0; k < 2; k++) {
    int s = tid + k * 512;
    rS[k] = s >> 3;
    cS[k] = (((s & 7) ^ (rS[k] & 7)) << 3);   // pre-swizzled source col
  }

#define STAGE128(t, buf) do { \
    int k0_ = (t) << 6; \
    _Pragma("unroll") \
    for (int k_ = 0; k_ < 2; k_++) \
      GLOAD16(A  + (size_t)(row0 + rS[k_]) * K + k0_ + cS[k_], \
              &sA[buf][(tid + k_ * 512) * 8]); \
    _Pragma("unroll") \
    for (int k_ = 0; k_ < 2; k_++) \
      GLOAD16(Bt + (size_t)(col0 + rS[k_]) * K + k0_ + cS[k_], \
              &sB[buf][(tid + k_ * 512) * 8]); \
  } while (0)

  STAGE128(0, 0);

  for (int t = 0; t < NT; t++) {
    const int cur = t & 1;
    if (t + 1 < NT) {
      STAGE128(t + 1, cur ^ 1);
      asm volatile("s_waitcnt vmcnt(4)" ::: "memory");
    } else {
      asm volatile("s_waitcnt vmcnt(0)" ::: "memory");
    }
    __builtin_amdgcn_s_barrier();
    __builtin_amdgcn_sched_barrier(0);

    const short* pA = &sA[cur][(wr * 64) * 64];
    const short* pB = &sB[cur][(wc * 32) * 64];
    #pragma unroll
    for (int ks = 0; ks < 2; ks++) {
      const int fswk = ((((ks << 2) | g) ^ (fr & 7)) << 3);
      short8v bfr[2], afr[4];
      #pragma unroll
      for (int ni = 0; ni < 2; ni++)
        bfr[ni] = *(const short8v*)(pB + (ni * 16 + fr) * 64 + fswk);
      #pragma unroll
      for (int m4 = 0; m4 < 4; m4++)
        afr[m4] = *(const short8v*)(pA + (m4 * 16 + fr) * 64 + fswk);
      __builtin_amdgcn_s_setprio(1);
      #pragma unroll
      for (int m4 = 0; m4 < 4; m4++)
        #pragma unroll
        for (int ni = 0; ni < 2; ni++)
          acc[m4][ni] = __builtin_amdgcn_mfma_f32_16x16x32_bf16(
              afr[m4], bfr[ni], acc[m4][ni], 0, 0, 0);
      __builtin_amdgcn_s_setprio(0);
    }
    asm volatile("" ::: "memory");
    __builtin_amdgcn_s_barrier();
  }

  #pragma unroll
  for (int m4 = 0; m4 < 4; m4++)
    #pragma unroll
    for (int ni = 0; ni < 2; ni++) {
      size_t base = (size_t)(row0 + wr * 64 + m4 * 16 + g * 4) * N
                    + col0 + wc * 32 + ni * 16 + fr;
      #pragma unroll
      for (int r = 0; r < 4; r++)
        C[base + (size_t)r * N] = acc[m4][ni][r];
    }
#undef STAGE128
}

// ======== gate_up GEMM + fused SwiGLU on the same schedule, vmcnt(6) ========
__global__ __launch_bounds__(512, 2)
void gemm_glu_big(const short* __restrict__ A, const short* __restrict__ Bt,
                  short* __restrict__ mlp, int K) {
  __shared__ short sA[2][128 * 64];
  __shared__ short sG[2][128 * 64];
  __shared__ short sU[2][128 * 64];
  int bx = blockIdx.x, by = blockIdx.y;
  xcd_swizzle(gridDim.x, gridDim.y, bx, by);
  const int tid  = threadIdx.x;
  const int lane = tid & 63;
  const int wv   = tid >> 6;
  const int wr   = wv >> 2;
  const int wc   = wv & 3;
  const int row0 = by * 128;
  const int col0 = bx * 128;
  const int fr = lane & 15;
  const int g  = lane >> 4;
  const int NT = K >> 6;

  float4v accg[4][2] = {};
  float4v accu[4][2] = {};

  int rS[2], cS[2];
  #pragma unroll
  for (int k = 0; k < 2; k++) {
    int s = tid + k * 512;
    rS[k] = s >> 3;
    cS[k] = (((s & 7) ^ (rS[k] & 7)) << 3);
  }

#define STAGEGLU(t, buf) do { \
    int k0_ = (t) << 6; \
    _Pragma("unroll") \
    for (int k_ = 0; k_ < 2; k_++) \
      GLOAD16(A  + (size_t)(row0 + rS[k_]) * K + k0_ + cS[k_], \
              &sA[buf][(tid + k_ * 512) * 8]); \
    _Pragma("unroll") \
    for (int k_ = 0; k_ < 2; k_++) \
      GLOAD16(Bt + (size_t)(col0 + rS[k_]) * K + k0_ + cS[k_], \
              &sG[buf][(tid + k_ * 512) * 8]); \
    _Pragma("unroll") \
    for (int k_ = 0; k_ < 2; k_++) \
      GLOAD16(Bt + (size_t)(col0 + I_ + rS[k_]) * K + k0_ + cS[k_], \
              &sU[buf][(tid + k_ * 512) * 8]); \
  } while (0)

  STAGEGLU(0, 0);

  for (int t = 0; t < NT; t++) {
    const int cur = t & 1;
    if (t + 1 < NT) {
      STAGEGLU(t + 1, cur ^ 1);
      asm volatile("s_waitcnt vmcnt(6)" ::: "memory");
    } else {
      asm volatile("s_waitcnt vmcnt(0)" ::: "memory");
    }
    __builtin_amdgcn_s_barrier();
    __builtin_amdgcn_sched_barrier(0);

    const short* pA = &sA[cur][(wr * 64) * 64];
    const short* pG = &sG[cur][(wc * 32) * 64];
    const short* pU = &sU[cur][(wc * 32) * 64];
    #pragma unroll
    for (int ks = 0; ks < 2; ks++) {
      const int fswk = ((((ks << 2) | g) ^ (fr & 7)) << 3);
      short8v bg[2], bu[2], afr[4];
      #pragma unroll
      for (int ni = 0; ni < 2; ni++) {
        bg[ni] = *(const short8v*)(pG + (ni * 16 + fr) * 64 + fswk);
        bu[ni] = *(const short8v*)(pU + (ni * 16 + fr) * 64 + fswk);
      }
      #pragma unroll
      for (int m4 = 0; m4 < 4; m4++)
        afr[m4] = *(const short8v*)(pA + (m4 * 16 + fr) * 64 + fswk);
      __builtin_amdgcn_s_setprio(1);
      #pragma unroll
      for (int m4 = 0; m4 < 4; m4++)
        #pragma unroll
        for (int ni = 0; ni < 2; ni++) {
          accg[m4][ni] = __builtin_amdgcn_mfma_f32_16x16x32_bf16(
              afr[m4], bg[ni], accg[m4][ni], 0, 0, 0);
          accu[m4][ni] = __builtin_amdgcn_mfma_f32_16x16x32_bf16(
              afr[m4], bu[ni], accu[m4][ni], 0, 0, 0);
        }
      __builtin_amdgcn_s_setprio(0);
    }
    asm volatile("" ::: "memory");
    __builtin_amdgcn_s_barrier();
  }

  #pragma unroll
  for (int m4 = 0; m4 < 4; m4++)
    #pragma unroll
    for (int ni = 0; ni < 2; ni++) {
      size_t base = (size_t)(row0 + wr * 64 + m4 * 16 + g * 4) * I_
                    + col0 + wc * 32 + ni * 16 + fr;
      #pragma unroll
      for (int r = 0; r < 4; r++) {
        float gv = accg[m4][ni][r], uv = accu[m4][ni][r];
        mlp[base + (size_t)r * I_] = f2bf(gv / (1.0f + __expf(-gv)) * uv);
      }
    }
#undef STAGEGLU
}

// ======== QKV GEMM on the counted-vmcnt schedule + fused RoPE epilogue ========
// Wave tile 32x64 (4M x 2N waves) so each wave's 64-col span = one head;
// RoPE pair (d, d+32) = acc n-tiles (jj, jj+2).  Schedule identical to
// gemm_big128 (vmcnt(4), T2 swizzle, setprio); only wave mapping + epilogue.
__global__ __launch_bounds__(512, 4)
void gemm_qkv_big(const short* __restrict__ A, const short* __restrict__ Bt,
                  const float* __restrict__ tab, short* __restrict__ qbf,
                  short* __restrict__ kbf, short* __restrict__ vbf, int K) {
  __shared__ short sA[2][128 * 64];
  __shared__ short sB[2][128 * 64];
  int bx = blockIdx.x, by = blockIdx.y;
  xcd_swizzle(gridDim.x, gridDim.y, bx, by);
  const int tid  = threadIdx.x;
  const int lane = tid & 63;
  const int wv   = tid >> 6;
  const int wm   = (wv >> 1) * 32;   // 4 M quarters of 32 rows
  const int wn   = (wv & 1) * 64;    // 2 N halves of 64 cols (one head)
  const int row0 = by * 128;
  const int col0 = bx * 128;
  const int fr = lane & 15;
  const int g  = lane >> 4;
  const int NT = K >> 6;

  float4v acc[2][4] = {};            // 32 VGPR

  int rS[2], cS[2];
  #pragma unroll
  for (int k = 0; k < 2; k++) {
    int s = tid + k * 512;
    rS[k] = s >> 3;
    cS[k] = (((s & 7) ^ (rS[k] & 7)) << 3);
  }

#define STAGEQKV(t, buf) do { \
    int k0_ = (t) << 6; \
    _Pragma("unroll") \
    for (int k_ = 0; k_ < 2; k_++) \
      GLOAD16(A  + (size_t)(row0 + rS[k_]) * K + k0_ + cS[k_], \
              &sA[buf][(tid + k_ * 512) * 8]); \
    _Pragma("unroll") \
    for (int k_ = 0; k_ < 2; k_++) \
      GLOAD16(Bt + (size_t)(col0 + rS[k_]) * K + k0_ + cS[k_], \
              &sB[buf][(tid + k_ * 512) * 8]); \
  } while (0)

  STAGEQKV(0, 0);

  for (int t = 0; t < NT; t++) {
    const int cur = t & 1;
    if (t + 1 < NT) {
      STAGEQKV(t + 1, cur ^ 1);
      asm volatile("s_waitcnt vmcnt(4)" ::: "memory");
    } else {
      asm volatile("s_waitcnt vmcnt(0)" ::: "memory");
    }
    __builtin_amdgcn_s_barrier();
    __builtin_amdgcn_sched_barrier(0);

    const short* pA = &sA[cur][wm * 64];
    const short* pB = &sB[cur][wn * 64];
    #pragma unroll
    for (int ks = 0; ks < 2; ks++) {
      const int fswk = ((((ks << 2) | g) ^ (fr & 7)) << 3);
      short8v afr[2], bfr[4];
      #pragma unroll
      for (int m2 = 0; m2 < 2; m2++)
        afr[m2] = *(const short8v*)(pA + (m2 * 16 + fr) * 64 + fswk);
      #pragma unroll
      for (int ni = 0; ni < 4; ni++)
        bfr[ni] = *(const short8v*)(pB + (ni * 16 + fr) * 64 + fswk);
      __builtin_amdgcn_s_setprio(1);
      #pragma unroll
      for (int m2 = 0; m2 < 2; m2++)
        #pragma unroll
        for (int ni = 0; ni < 4; ni++)
          acc[m2][ni] = __builtin_amdgcn_mfma_f32_16x16x32_bf16(
              afr[m2], bfr[ni], acc[m2][ni], 0, 0, 0);
      __builtin_amdgcn_s_setprio(0);
    }
    asm volatile("" ::: "memory");
    __builtin_amdgcn_s_barrier();
  }

  const int head = (col0 + wn) >> 6;
  if (head < HQ_ + HKV_) {
    const float sc = (head < HQ_) ? SCALE_ : 1.0f;
    short* dst = (head < HQ_) ? qbf : kbf;
    const int hh = (head < HQ_) ? head : head - HQ_;
    const int HN = (head < HQ_) ? HQ_ : HKV_;
    #pragma unroll
    for (int m2 = 0; m2 < 2; m2++)
      #pragma unroll
      for (int jj = 0; jj < 2; jj++)
        #pragma unroll
        for (int r = 0; r < 4; r++) {
          int m = row0 + wm + m2 * 16 + g * 4 + r;
          int b = m >> 10, s = m & (S_ - 1);
          int d1 = jj * 16 + fr;
          float x1 = acc[m2][jj][r], x2 = acc[m2][jj + 2][r];
          const float* tb = tab + (size_t)m * 64 + d1 * 2;
          float c = tb[0], sn = tb[1];
          size_t base = ((size_t)((b * HN + hh) * S_ + s)) * HD_;
          dst[base + d1]      = f2bf((x1 * c - x2 * sn) * sc);
          dst[base + d1 + 32] = f2bf((x2 * c + x1 * sn) * sc);
        }
  } else {
    const int vh = head - HQ_ - HKV_;
    #pragma unroll
    for (int m2 = 0; m2 < 2; m2++)
      #pragma unroll
      for (int ni = 0; ni < 4; ni++)
        #pragma unroll
        for (int r = 0; r < 4; r++) {
          int m = row0 + wm + m2 * 16 + g * 4 + r;
          int b = m >> 10, s = m & (S_ - 1);
          vbf[((size_t)((b * HKV_ + vh) * S_ + s)) * HD_ + ni * 16 + fr] =
              f2bf(acc[m2][ni][r]);
        }
  }
#undef STAGEQKV
}

// ---------------- RoPE cos/sin table: [T][32][2] f32 ----------------
__global__ __launch_bounds__(256)
void rope_table(const int* __restrict__ pos, float* __restrict__ tab) {
  int i = blockIdx.x * 256 + threadIdx.x;
  int t = i >> 5, ii = i & 31;
  float p = (float)pos[t];
  float freq = __expf(-(float)ii * (9.210340371976184f / 32.0f));
  float ang = p * freq;
  tab[2 * i]     = cosf(ang);
  tab[2 * i + 1] = sinf(ang);
}

// ---------------- V transpose: vbf [bkh][j][d] -> vtbf [bkh][d][j] ----------------
#define KPAD 68

__global__ __launch_bounds__(256)
void transpose_v(const short* __restrict__ vbf, short* __restrict__ vtbf) {
  __shared__ short sv[64 * KPAD];
  const int jt = blockIdx.x, kh = blockIdx.y, b = blockIdx.z;
  const int tid = threadIdx.x;
  const short* src = vbf + ((size_t)((b * HKV_ + kh) * S_ + jt * 64)) * HD_;
  #pragma unroll
  for (int it = 0; it < 2; it++) {
    int c = it * 256 + tid;
    int rr = c >> 3, ch = (c & 7) * 8;
    *(short8v*)(&sv[rr * KPAD + ch]) = *(const short8v*)(src + (size_t)rr * HD_ + ch);
  }
  __syncthreads();
  const int dc = tid >> 2;
  const int jc = (tid & 3) * 16;
  short8v o1, o2;
  #pragma unroll
  for (int k = 0; k < 8; k++) o1[k] = sv[(jc + k) * KPAD + dc];
  #pragma unroll
  for (int k = 0; k < 8; k++) o2[k] = sv[(jc + 8 + k) * KPAD + dc];
  short* od = vtbf + ((size_t)((b * HKV_ + kh) * HD_ + dc)) * S_ + jt * 64 + jc;
  *(short8v*)od       = o1;
  *(short8v*)(od + 8) = o2;
}

// ---------------- MFMA flash attention (bf16 out) ----------------
__global__ __launch_bounds__(256)
void attn_mfma(const short* __restrict__ qbf, const short* __restrict__ kbf,
               const short* __restrict__ vtbf, short* __restrict__ obf) {
  __shared__ short sK[64 * KPAD];
  __shared__ short sVt[64 * KPAD];
  __shared__ short sP[4][16 * KPAD];
  const int qb = blockIdx.x;
  const int h  = blockIdx.y;
  const int b  = blockIdx.z;
  const int kh = h >> 2;
  const int tid  = threadIdx.x;
  const int lane = tid & 63;
  const int wv   = tid >> 6;
  const int q0 = qb * 64;
  const int cc = lane & 15;
  const int g  = lane >> 4;

  short8v qf0, qf1;
  {
    const short* qrow = qbf + ((size_t)((b * HQ_ + h) * S_ + q0 + wv * 16 + cc)) * HD_;
    qf0 = *(const short8v*)(qrow + g * 8);
    qf1 = *(const short8v*)(qrow + g * 8 + 32);
  }
  float4v accO[4] = {};
  float m_r[4], l_r[4];
  #pragma unroll
  for (int r = 0; r < 4; r++) { m_r[r] = -1e30f; l_r[r] = 0.f; }

  const short* kb = kbf  + ((size_t)(b * HKV_ + kh)) * S_ * HD_;
  const short* vb = vtbf + ((size_t)(b * HKV_ + kh)) * HD_ * S_;

  for (int jt = 0; jt <= qb; jt++) {
    const int j0 = jt * 64;
    #pragma unroll
    for (int it = 0; it < 2; it++) {
      int idx = it * 256 + tid;
      int rr = idx >> 3, ch = (idx & 7) * 8;
      *(short8v*)(&sK[rr * KPAD + ch])  = *(const short8v*)(kb + (size_t)(j0 + rr) * HD_ + ch);
      *(short8v*)(&sVt[rr * KPAD + ch]) = *(const short8v*)(vb + (size_t)rr * S_ + j0 + ch);
    }
    __syncthreads();

    float4v sc[4] = {};
    #pragma unroll
    for (int ct = 0; ct < 4; ct++) {
      short8v k0 = *(const short8v*)(&sK[(ct * 16 + cc) * KPAD + g * 8]);
      short8v k1 = *(const short8v*)(&sK[(ct * 16 + cc) * KPAD + g * 8 + 32]);
      sc[ct] = __builtin_amdgcn_mfma_f32_16x16x32_bf16(qf0, k0, sc[ct], 0, 0, 0);
      sc[ct] = __builtin_amdgcn_mfma_f32_16x16x32_bf16(qf1, k1, sc[ct], 0, 0, 0);
    }
    if (jt == qb) {
      #pragma unroll
      for (int ct = 0; ct < 4; ct++)
        #pragma unroll
        for (int r = 0; r < 4; r++)
          if (j0 + ct * 16 + cc > q0 + wv * 16 + g * 4 + r) sc[ct][r] = -1e30f;
    }
    float corr[4];
    #pragma unroll
    for (int r = 0; r < 4; r++) {
      float pm = fmaxf(fmaxf(sc[0][r], sc[1][r]), fmaxf(sc[2][r], sc[3][r]));
      pm = fmaxf(pm, __shfl_xor(pm, 1, 64));
      pm = fmaxf(pm, __shfl_xor(pm, 2, 64));
      pm = fmaxf(pm, __shfl_xor(pm, 4, 64));
      pm = fmaxf(pm, __shfl_xor(pm, 8, 64));
      float mn = fmaxf(m_r[r], pm);
      corr[r] = __expf(m_r[r] - mn);
      m_r[r] = mn;
      float rs = 0.f;
      #pragma unroll
      for (int ct = 0; ct < 4; ct++) {
        float p = __expf(sc[ct][r] - mn);
        sc[ct][r] = p;
        rs += p;
      }
      rs += __shfl_xor(rs, 1, 64);
      rs += __shfl_xor(rs, 2, 64);
      rs += __shfl_xor(rs, 4, 64);
      rs += __shfl_xor(rs, 8, 64);
      l_r[r] = l_r[r] * corr[r] + rs;
    }
    #pragma unroll
    for (int ct = 0; ct < 4; ct++)
      #pragma unroll
      for (int r = 0; r < 4; r++)
        sP[wv][(g * 4 + r) * KPAD + ct * 16 + cc] = f2bf(sc[ct][r]);
    #pragma unroll
    for (int dt = 0; dt < 4; dt++)
      #pragma unroll
      for (int r = 0; r < 4; r++)
        accO[dt][r] *= corr[r];
    short8v pf0 = *(const short8v*)(&sP[wv][cc * KPAD + g * 8]);
    short8v pf1 = *(const short8v*)(&sP[wv][cc * KPAD + g * 8 + 32]);
    #pragma unroll
    for (int dt = 0; dt < 4; dt++) {
      short8v v0 = *(const short8v*)(&sVt[(dt * 16 + cc) * KPAD + g * 8]);
      short8v v1 = *(const short8v*)(&sVt[(dt * 16 + cc) * KPAD + g * 8 + 32]);
      accO[dt] = __builtin_amdgcn_mfma_f32_16x16x32_bf16(pf0, v0, accO[dt], 0, 0, 0);
      accO[dt] = __builtin_amdgcn_mfma_f32_16x16x32_bf16(pf1, v1, accO[dt], 0, 0, 0);
    }
    __syncthreads();
  }
  #pragma unroll
  for (int dt = 0; dt < 4; dt++)
    #pragma unroll
    for (int r = 0; r < 4; r++) {
      int q = q0 + wv * 16 + g * 4 + r;
      obf[((size_t)(b * S_ + q)) * 2048 + h * 64 + dt * 16 + cc] = f2bf(accO[dt][r] / l_r[r]);
    }
}

// ---------------- launch ----------------
extern "C" void kernel_launch(void* const* d_in, const int* in_sizes, int n_in,
                              void* d_out, int out_size, void* d_ws, size_t ws_size,
                              hipStream_t stream) {
  const int*   ids   = (const int*)d_in[0];
  const int*   pos   = (const int*)d_in[1];
  const float* embed = (const float*)d_in[2];
  const float* w_qkv = (const float*)d_in[3];
  const float* w_o   = (const float*)d_in[4];
  const float* w_gu  = (const float*)d_in[5];
  const float* w_dn  = (const float*)d_in[6];
  const float* ln1   = (const float*)d_in[7];
  const float* ln2   = (const float*)d_in[8];
  const float* normw = (const float*)d_in[9];
  float* out = (float*)d_out;

  char* p = (char*)d_ws;
  short* wT    = (short*)p; p += (size_t)11264 * 2048 * 2;
  float* h     = (float*)p; p += (size_t)T_ * D_ * 4;
  float* res   = (float*)p; p += (size_t)T_ * D_ * 4;
  short* hnbf  = (short*)p; p += (size_t)T_ * D_ * 2;
  short* obf   = (short*)p; p += (size_t)T_ * D_ * 2;
  short* mlpbf = (short*)p; p += (size_t)T_ * I_ * 2;
  float* tab   = (float*)p; p += (size_t)T_ * 64 * 4;
  short* qbf   = (short*)p; p += (size_t)B_ * HQ_ * S_ * HD_ * 2;
  short* kbf   = (short*)p; p += (size_t)B_ * HKV_ * S_ * HD_ * 2;
  short* vbf   = (short*)p; p += (size_t)B_ * HKV_ * S_ * HD_ * 2;
  short* vtbf  = (short*)p; p += (size_t)B_ * HKV_ * HD_ * S_ * 2;

  embed_gather<<<T_ * D_ / 4 / 256, 256, 0, stream>>>(ids, embed, h);
  rope_table<<<T_ * 32 / 256, 256, 0, stream>>>(pos, tab);

  for (int l = 0; l < L_; l++) {
    rmsnorm_add<<<T_, 256, 0, stream>>>(h, res, ln1 + l * D_, hnbf, l == 0 ? 1 : 0, 1);

    transpose_bf16<<<dim3(3072 / 64, 2048 / 64), 256, 0, stream>>>(
        w_qkv + (size_t)l * 2048 * 3072, wT, 2048, 3072);
    gemm_qkv_big<<<dim3(3072 / 128, T_ / 128), 512, 0, stream>>>(
        hnbf, wT, tab, qbf, kbf, vbf, 2048);

    transpose_v<<<dim3(16, 8, 2), 256, 0, stream>>>(vbf, vtbf);
    attn_mfma<<<dim3(16, 32, 2), 256, 0, stream>>>(qbf, kbf, vtbf, obf);

    transpose_bf16<<<dim3(2048 / 64, 2048 / 64), 256, 0, stream>>>(
        w_o + (size_t)l * 2048 * 2048, wT, 2048, 2048);
    gemm_big128<<<dim3(2048 / 128, T_ / 128), 512, 0, stream>>>(
        obf, wT, h, T_, 2048, 2048);

    rmsnorm_add<<<T_, 256, 0, stream>>>(h, res, ln2 + l * D_, hnbf, 0, 1);

    transpose_bf16<<<dim3(11264 / 64, 2048 / 64), 256, 0, stream>>>(
        w_gu + (size_t)l * 2048 * 11264, wT, 2048, 11264);
    gemm_glu_big<<<dim3(I_ / 128, T_ / 128), 512, 0, stream>>>(
        hnbf, wT, mlpbf, 2048);

    transpose_bf16<<<dim3(2048 / 64, 5632 / 64), 256, 0, stream>>>(
        w_dn + (size_t)l * 5632 * 2048, wT, 5632, 2048);
    gemm_big128<<<dim3(2048 / 128, T_ / 128), 512, 0, stream>>>(
        mlpbf, wT, h, T_, 2048, 5632);
  }
  rmsnorm_add<<<T_, 256, 0, stream>>>(h, res, normw, out, 0, 0);
}

// Round 10
// 1739.914 us; speedup vs baseline: 1.1592x; 1.0152x over previous
//
#include <hip/hip_runtime.h>
#include <hip/hip_bf16.h>

#define B_ 2
#define S_ 1024
#define T_ (B_*S_)
#define D_ 2048
#define L_ 4
#define HQ_ 32
#define HKV_ 8
#define HD_ 64
#define I_ 5632
#define EPS_ 1e-5f
#define SCALE_ 0.125f

typedef __attribute__((ext_vector_type(4))) float  float4v;
typedef __attribute__((ext_vector_type(8))) short  short8v;

#define GLOAD16(g, l) \
  __builtin_amdgcn_global_load_lds((const __attribute__((address_space(1))) void*)(g), \
                                   (__attribute__((address_space(3))) void*)(l), 16, 0, 0)

__device__ __forceinline__ short f2bf(float f) {
  union { float f; unsigned u; } c; c.f = f;
  unsigned u = c.u + 0x7fffu + ((c.u >> 16) & 1u);
  return (short)(u >> 16);
}

// bijective XCD-aware block swizzle (m204), column-major decode
__device__ __forceinline__ void xcd_swizzle(int gx, int gy, int& bx, int& by) {
  int nwg = gx * gy;
  int orig = by * gx + bx;
  int q = nwg >> 3, r = nwg & 7;
  int xcd = orig & 7, loc = orig >> 3;
  int swz = (xcd < r ? xcd * (q + 1) : r * (q + 1) + (xcd - r) * q) + loc;
  bx = swz / gy;
  by = swz - bx * gy;
}

// ---------------- transpose f32 [K][N] -> bf16 [N][K], 64x64 vectorized ----------------
__global__ __launch_bounds__(256)
void transpose_bf16(const float* __restrict__ in, short* __restrict__ out,
                    int K, int N) {
  __shared__ float t[64][65];
  const int bx = blockIdx.x * 64;   // N
  const int by = blockIdx.y * 64;   // K
  const int tid = threadIdx.x;
  const int lr = tid >> 4;
  const int lc = (tid & 15) * 4;
  #pragma unroll
  for (int j = 0; j < 64; j += 16) {
    float4v v = *(const float4v*)(in + (size_t)(by + lr + j) * N + bx + lc);
    t[lr + j][lc] = v[0]; t[lr + j][lc + 1] = v[1];
    t[lr + j][lc + 2] = v[2]; t[lr + j][lc + 3] = v[3];
  }
  __syncthreads();
  const int nr = tid >> 3;
  const int kc = (tid & 7) * 8;
  #pragma unroll
  for (int j = 0; j < 64; j += 32) {
    short8v y;
    #pragma unroll
    for (int e = 0; e < 8; e++) y[e] = f2bf(t[kc + e][nr + j]);
    *(short8v*)(out + (size_t)(bx + nr + j) * K + by + kc) = y;
  }
}

// ---------------- embedding gather ----------------
__global__ __launch_bounds__(256)
void embed_gather(const int* __restrict__ ids, const float* __restrict__ embed,
                  float* __restrict__ h) {
  size_t i = (size_t)blockIdx.x * 256 + threadIdx.x;
  int t  = (int)(i >> 9);
  int d4 = (int)(i & 511);
  ((float4v*)h)[i] = ((const float4v*)(embed + (size_t)ids[t] * D_))[d4];
}

// ---------------- fused residual-add + RMSNorm (bf16 or f32 out) ----------------
__global__ __launch_bounds__(256)
void rmsnorm_add(const float* __restrict__ x, float* __restrict__ res,
                 const float* __restrict__ w, void* __restrict__ outp,
                 int first, int bf16out) {
  const int row = blockIdx.x;
  const int tid = threadIdx.x;
  const size_t base = (size_t)row * D_;
  float4v v0 = ((const float4v*)(x + base))[tid * 2];
  float4v v1 = ((const float4v*)(x + base))[tid * 2 + 1];
  if (!first) {
    v0 += ((const float4v*)(res + base))[tid * 2];
    v1 += ((const float4v*)(res + base))[tid * 2 + 1];
  }
  ((float4v*)(res + base))[tid * 2]     = v0;
  ((float4v*)(res + base))[tid * 2 + 1] = v1;
  float ss = v0[0]*v0[0] + v0[1]*v0[1] + v0[2]*v0[2] + v0[3]*v0[3]
           + v1[0]*v1[0] + v1[1]*v1[1] + v1[2]*v1[2] + v1[3]*v1[3];
  #pragma unroll
  for (int off = 32; off > 0; off >>= 1) ss += __shfl_xor(ss, off, 64);
  __shared__ float red[4];
  if ((tid & 63) == 0) red[tid >> 6] = ss;
  __syncthreads();
  float tot = red[0] + red[1] + red[2] + red[3];
  float rs = rsqrtf(tot * (1.0f / D_) + EPS_);
  float4v w0 = ((const float4v*)w)[tid * 2];
  float4v w1 = ((const float4v*)w)[tid * 2 + 1];
  float4v o0 = v0 * rs * w0;
  float4v o1 = v1 * rs * w1;
  if (bf16out) {
    short8v y;
    #pragma unroll
    for (int k = 0; k < 4; k++) { y[k] = f2bf(o0[k]); y[k + 4] = f2bf(o1[k]); }
    ((short8v*)((char*)outp + base * 2))[tid] = y;
  } else {
    float* op = (float*)outp + base;
    ((float4v*)op)[tid * 2]     = o0;
    ((float4v*)op)[tid * 2 + 1] = o1;
  }
}

// ======== 128x128 8-wave GEMM, counted vmcnt(4) + T2 swizzle + setprio ========
// LDS 64KB dbuf -> 2 blocks/CU.  Wave tile 64x32 (2M x 4N waves).
__global__ __launch_bounds__(512, 4)
void gemm_big128(const short* __restrict__ A, const short* __restrict__ Bt,
                 float* __restrict__ C, int M, int N, int K) {
  __shared__ short sA[2][128 * 64];
  __shared__ short sB[2][128 * 64];
  int bx = blockIdx.x, by = blockIdx.y;
  xcd_swizzle(gridDim.x, gridDim.y, bx, by);
  const int tid  = threadIdx.x;
  const int lane = tid & 63;
  const int wv   = tid >> 6;
  const int wr   = wv >> 2;          // 0..1
  const int wc   = wv & 3;           // 0..3
  const int row0 = by * 128;
  const int col0 = bx * 128;
  const int fr = lane & 15;
  const int g  = lane >> 4;
  const int NT = K >> 6;

  float4v acc[4][2] = {};            // 32 VGPR

  int rS[2], cS[2];
  #pragma unroll
  for (int k = 0; k < 2; k++) {
    int s = tid + k * 512;
    rS[k] = s >> 3;
    cS[k] = (((s & 7) ^ (rS[k] & 7)) << 3);   // pre-swizzled source col
  }

#define STAGE128(t, buf) do { \
    int k0_ = (t) << 6; \
    _Pragma("unroll") \
    for (int k_ = 0; k_ < 2; k_++) \
      GLOAD16(A  + (size_t)(row0 + rS[k_]) * K + k0_ + cS[k_], \
              &sA[buf][(tid + k_ * 512) * 8]); \
    _Pragma("unroll") \
    for (int k_ = 0; k_ < 2; k_++) \
      GLOAD16(Bt + (size_t)(col0 + rS[k_]) * K + k0_ + cS[k_], \
              &sB[buf][(tid + k_ * 512) * 8]); \
  } while (0)

  STAGE128(0, 0);

  for (int t = 0; t < NT; t++) {
    const int cur = t & 1;
    if (t + 1 < NT) {
      STAGE128(t + 1, cur ^ 1);
      asm volatile("s_waitcnt vmcnt(4)" ::: "memory");
    } else {
      asm volatile("s_waitcnt vmcnt(0)" ::: "memory");
    }
    __builtin_amdgcn_s_barrier();
    __builtin_amdgcn_sched_barrier(0);

    const short* pA = &sA[cur][(wr * 64) * 64];
    const short* pB = &sB[cur][(wc * 32) * 64];
    #pragma unroll
    for (int ks = 0; ks < 2; ks++) {
      const int fswk = ((((ks << 2) | g) ^ (fr & 7)) << 3);
      short8v bfr[2], afr[4];
      #pragma unroll
      for (int ni = 0; ni < 2; ni++)
        bfr[ni] = *(const short8v*)(pB + (ni * 16 + fr) * 64 + fswk);
      #pragma unroll
      for (int m4 = 0; m4 < 4; m4++)
        afr[m4] = *(const short8v*)(pA + (m4 * 16 + fr) * 64 + fswk);
      __builtin_amdgcn_s_setprio(1);
      #pragma unroll
      for (int m4 = 0; m4 < 4; m4++)
        #pragma unroll
        for (int ni = 0; ni < 2; ni++)
          acc[m4][ni] = __builtin_amdgcn_mfma_f32_16x16x32_bf16(
              afr[m4], bfr[ni], acc[m4][ni], 0, 0, 0);
      __builtin_amdgcn_s_setprio(0);
    }
    asm volatile("" ::: "memory");
    __builtin_amdgcn_s_barrier();
  }

  #pragma unroll
  for (int m4 = 0; m4 < 4; m4++)
    #pragma unroll
    for (int ni = 0; ni < 2; ni++) {
      size_t base = (size_t)(row0 + wr * 64 + m4 * 16 + g * 4) * N
                    + col0 + wc * 32 + ni * 16 + fr;
      #pragma unroll
      for (int r = 0; r < 4; r++)
        C[base + (size_t)r * N] = acc[m4][ni][r];
    }
#undef STAGE128
}

// ======== gate_up GEMM + fused SwiGLU on the same schedule, vmcnt(6) ========
__global__ __launch_bounds__(512, 2)
void gemm_glu_big(const short* __restrict__ A, const short* __restrict__ Bt,
                  short* __restrict__ mlp, int K) {
  __shared__ short sA[2][128 * 64];
  __shared__ short sG[2][128 * 64];
  __shared__ short sU[2][128 * 64];
  int bx = blockIdx.x, by = blockIdx.y;
  xcd_swizzle(gridDim.x, gridDim.y, bx, by);
  const int tid  = threadIdx.x;
  const int lane = tid & 63;
  const int wv   = tid >> 6;
  const int wr   = wv >> 2;
  const int wc   = wv & 3;
  const int row0 = by * 128;
  const int col0 = bx * 128;
  const int fr = lane & 15;
  const int g  = lane >> 4;
  const int NT = K >> 6;

  float4v accg[4][2] = {};
  float4v accu[4][2] = {};

  int rS[2], cS[2];
  #pragma unroll
  for (int k = 0; k < 2; k++) {
    int s = tid + k * 512;
    rS[k] = s >> 3;
    cS[k] = (((s & 7) ^ (rS[k] & 7)) << 3);
  }

#define STAGEGLU(t, buf) do { \
    int k0_ = (t) << 6; \
    _Pragma("unroll") \
    for (int k_ = 0; k_ < 2; k_++) \
      GLOAD16(A  + (size_t)(row0 + rS[k_]) * K + k0_ + cS[k_], \
              &sA[buf][(tid + k_ * 512) * 8]); \
    _Pragma("unroll") \
    for (int k_ = 0; k_ < 2; k_++) \
      GLOAD16(Bt + (size_t)(col0 + rS[k_]) * K + k0_ + cS[k_], \
              &sG[buf][(tid + k_ * 512) * 8]); \
    _Pragma("unroll") \
    for (int k_ = 0; k_ < 2; k_++) \
      GLOAD16(Bt + (size_t)(col0 + I_ + rS[k_]) * K + k0_ + cS[k_], \
              &sU[buf][(tid + k_ * 512) * 8]); \
  } while (0)

  STAGEGLU(0, 0);

  for (int t = 0; t < NT; t++) {
    const int cur = t & 1;
    if (t + 1 < NT) {
      STAGEGLU(t + 1, cur ^ 1);
      asm volatile("s_waitcnt vmcnt(6)" ::: "memory");
    } else {
      asm volatile("s_waitcnt vmcnt(0)" ::: "memory");
    }
    __builtin_amdgcn_s_barrier();
    __builtin_amdgcn_sched_barrier(0);

    const short* pA = &sA[cur][(wr * 64) * 64];
    const short* pG = &sG[cur][(wc * 32) * 64];
    const short* pU = &sU[cur][(wc * 32) * 64];
    #pragma unroll
    for (int ks = 0; ks < 2; ks++) {
      const int fswk = ((((ks << 2) | g) ^ (fr & 7)) << 3);
      short8v bg[2], bu[2], afr[4];
      #pragma unroll
      for (int ni = 0; ni < 2; ni++) {
        bg[ni] = *(const short8v*)(pG + (ni * 16 + fr) * 64 + fswk);
        bu[ni] = *(const short8v*)(pU + (ni * 16 + fr) * 64 + fswk);
      }
      #pragma unroll
      for (int m4 = 0; m4 < 4; m4++)
        afr[m4] = *(const short8v*)(pA + (m4 * 16 + fr) * 64 + fswk);
      __builtin_amdgcn_s_setprio(1);
      #pragma unroll
      for (int m4 = 0; m4 < 4; m4++)
        #pragma unroll
        for (int ni = 0; ni < 2; ni++) {
          accg[m4][ni] = __builtin_amdgcn_mfma_f32_16x16x32_bf16(
              afr[m4], bg[ni], accg[m4][ni], 0, 0, 0);
          accu[m4][ni] = __builtin_amdgcn_mfma_f32_16x16x32_bf16(
              afr[m4], bu[ni], accu[m4][ni], 0, 0, 0);
        }
      __builtin_amdgcn_s_setprio(0);
    }
    asm volatile("" ::: "memory");
    __builtin_amdgcn_s_barrier();
  }

  #pragma unroll
  for (int m4 = 0; m4 < 4; m4++)
    #pragma unroll
    for (int ni = 0; ni < 2; ni++) {
      size_t base = (size_t)(row0 + wr * 64 + m4 * 16 + g * 4) * I_
                    + col0 + wc * 32 + ni * 16 + fr;
      #pragma unroll
      for (int r = 0; r < 4; r++) {
        float gv = accg[m4][ni][r], uv = accu[m4][ni][r];
        mlp[base + (size_t)r * I_] = f2bf(gv / (1.0f + __expf(-gv)) * uv);
      }
    }
#undef STAGEGLU
}

// ======== QKV GEMM on the counted-vmcnt schedule + fused RoPE epilogue ========
__global__ __launch_bounds__(512, 4)
void gemm_qkv_big(const short* __restrict__ A, const short* __restrict__ Bt,
                  const float* __restrict__ tab, short* __restrict__ qbf,
                  short* __restrict__ kbf, short* __restrict__ vbf, int K) {
  __shared__ short sA[2][128 * 64];
  __shared__ short sB[2][128 * 64];
  int bx = blockIdx.x, by = blockIdx.y;
  xcd_swizzle(gridDim.x, gridDim.y, bx, by);
  const int tid  = threadIdx.x;
  const int lane = tid & 63;
  const int wv   = tid >> 6;
  const int wm   = (wv >> 1) * 32;   // 4 M quarters of 32 rows
  const int wn   = (wv & 1) * 64;    // 2 N halves of 64 cols (one head)
  const int row0 = by * 128;
  const int col0 = bx * 128;
  const int fr = lane & 15;
  const int g  = lane >> 4;
  const int NT = K >> 6;

  float4v acc[2][4] = {};            // 32 VGPR

  int rS[2], cS[2];
  #pragma unroll
  for (int k = 0; k < 2; k++) {
    int s = tid + k * 512;
    rS[k] = s >> 3;
    cS[k] = (((s & 7) ^ (rS[k] & 7)) << 3);
  }

#define STAGEQKV(t, buf) do { \
    int k0_ = (t) << 6; \
    _Pragma("unroll") \
    for (int k_ = 0; k_ < 2; k_++) \
      GLOAD16(A  + (size_t)(row0 + rS[k_]) * K + k0_ + cS[k_], \
              &sA[buf][(tid + k_ * 512) * 8]); \
    _Pragma("unroll") \
    for (int k_ = 0; k_ < 2; k_++) \
      GLOAD16(Bt + (size_t)(col0 + rS[k_]) * K + k0_ + cS[k_], \
              &sB[buf][(tid + k_ * 512) * 8]); \
  } while (0)

  STAGEQKV(0, 0);

  for (int t = 0; t < NT; t++) {
    const int cur = t & 1;
    if (t + 1 < NT) {
      STAGEQKV(t + 1, cur ^ 1);
      asm volatile("s_waitcnt vmcnt(4)" ::: "memory");
    } else {
      asm volatile("s_waitcnt vmcnt(0)" ::: "memory");
    }
    __builtin_amdgcn_s_barrier();
    __builtin_amdgcn_sched_barrier(0);

    const short* pA = &sA[cur][wm * 64];
    const short* pB = &sB[cur][wn * 64];
    #pragma unroll
    for (int ks = 0; ks < 2; ks++) {
      const int fswk = ((((ks << 2) | g) ^ (fr & 7)) << 3);
      short8v afr[2], bfr[4];
      #pragma unroll
      for (int m2 = 0; m2 < 2; m2++)
        afr[m2] = *(const short8v*)(pA + (m2 * 16 + fr) * 64 + fswk);
      #pragma unroll
      for (int ni = 0; ni < 4; ni++)
        bfr[ni] = *(const short8v*)(pB + (ni * 16 + fr) * 64 + fswk);
      __builtin_amdgcn_s_setprio(1);
      #pragma unroll
      for (int m2 = 0; m2 < 2; m2++)
        #pragma unroll
        for (int ni = 0; ni < 4; ni++)
          acc[m2][ni] = __builtin_amdgcn_mfma_f32_16x16x32_bf16(
              afr[m2], bfr[ni], acc[m2][ni], 0, 0, 0);
      __builtin_amdgcn_s_setprio(0);
    }
    asm volatile("" ::: "memory");
    __builtin_amdgcn_s_barrier();
  }

  const int head = (col0 + wn) >> 6;
  if (head < HQ_ + HKV_) {
    const float sc = (head < HQ_) ? SCALE_ : 1.0f;
    short* dst = (head < HQ_) ? qbf : kbf;
    const int hh = (head < HQ_) ? head : head - HQ_;
    const int HN = (head < HQ_) ? HQ_ : HKV_;
    #pragma unroll
    for (int m2 = 0; m2 < 2; m2++)
      #pragma unroll
      for (int jj = 0; jj < 2; jj++)
        #pragma unroll
        for (int r = 0; r < 4; r++) {
          int m = row0 + wm + m2 * 16 + g * 4 + r;
          int b = m >> 10, s = m & (S_ - 1);
          int d1 = jj * 16 + fr;
          float x1 = acc[m2][jj][r], x2 = acc[m2][jj + 2][r];
          const float* tb = tab + (size_t)m * 64 + d1 * 2;
          float c = tb[0], sn = tb[1];
          size_t base = ((size_t)((b * HN + hh) * S_ + s)) * HD_;
          dst[base + d1]      = f2bf((x1 * c - x2 * sn) * sc);
          dst[base + d1 + 32] = f2bf((x2 * c + x1 * sn) * sc);
        }
  } else {
    const int vh = head - HQ_ - HKV_;
    #pragma unroll
    for (int m2 = 0; m2 < 2; m2++)
      #pragma unroll
      for (int ni = 0; ni < 4; ni++)
        #pragma unroll
        for (int r = 0; r < 4; r++) {
          int m = row0 + wm + m2 * 16 + g * 4 + r;
          int b = m >> 10, s = m & (S_ - 1);
          vbf[((size_t)((b * HKV_ + vh) * S_ + s)) * HD_ + ni * 16 + fr] =
              f2bf(acc[m2][ni][r]);
        }
  }
#undef STAGEQKV
}

// ---------------- RoPE cos/sin table: [T][32][2] f32 ----------------
__global__ __launch_bounds__(256)
void rope_table(const int* __restrict__ pos, float* __restrict__ tab) {
  int i = blockIdx.x * 256 + threadIdx.x;
  int t = i >> 5, ii = i & 31;
  float p = (float)pos[t];
  float freq = __expf(-(float)ii * (9.210340371976184f / 32.0f));
  float ang = p * freq;
  tab[2 * i]     = cosf(ang);
  tab[2 * i + 1] = sinf(ang);
}

// ---------------- V transpose: vbf [bkh][j][d] -> vtbf [bkh][d][j] ----------------
#define KPAD 68

__global__ __launch_bounds__(256)
void transpose_v(const short* __restrict__ vbf, short* __restrict__ vtbf) {
  __shared__ short sv[64 * KPAD];
  const int jt = blockIdx.x, kh = blockIdx.y, b = blockIdx.z;
  const int tid = threadIdx.x;
  const short* src = vbf + ((size_t)((b * HKV_ + kh) * S_ + jt * 64)) * HD_;
  #pragma unroll
  for (int it = 0; it < 2; it++) {
    int c = it * 256 + tid;
    int rr = c >> 3, ch = (c & 7) * 8;
    *(short8v*)(&sv[rr * KPAD + ch]) = *(const short8v*)(src + (size_t)rr * HD_ + ch);
  }
  __syncthreads();
  const int dc = tid >> 2;
  const int jc = (tid & 3) * 16;
  short8v o1, o2;
  #pragma unroll
  for (int k = 0; k < 8; k++) o1[k] = sv[(jc + k) * KPAD + dc];
  #pragma unroll
  for (int k = 0; k < 8; k++) o2[k] = sv[(jc + 8 + k) * KPAD + dc];
  short* od = vtbf + ((size_t)((b * HKV_ + kh) * HD_ + dc)) * S_ + jt * 64 + jc;
  *(short8v*)od       = o1;
  *(short8v*)(od + 8) = o2;
}

// ---------------- MFMA flash attention, T14 async-STAGE split ----------------
// Per tile: write previously-loaded regs -> LDS, sync, ISSUE next tile's
// global loads, then compute (loads' latency hides under QK/softmax/PV).
// Single LDS buffer, 2 barriers/tile, compiler-managed waitcnts only.
__global__ __launch_bounds__(256)
void attn_mfma(const short* __restrict__ qbf, const short* __restrict__ kbf,
               const short* __restrict__ vtbf, short* __restrict__ obf) {
  __shared__ short sK[64 * KPAD];
  __shared__ short sVt[64 * KPAD];
  __shared__ short sP[4][16 * KPAD];
  const int qb = blockIdx.x;
  const int h  = blockIdx.y;
  const int b  = blockIdx.z;
  const int kh = h >> 2;
  const int tid  = threadIdx.x;
  const int lane = tid & 63;
  const int wv   = tid >> 6;
  const int q0 = qb * 64;
  const int cc = lane & 15;
  const int g  = lane >> 4;

  short8v qf0, qf1;
  {
    const short* qrow = qbf + ((size_t)((b * HQ_ + h) * S_ + q0 + wv * 16 + cc)) * HD_;
    qf0 = *(const short8v*)(qrow + g * 8);
    qf1 = *(const short8v*)(qrow + g * 8 + 32);
  }
  float4v accO[4] = {};
  float m_r[4], l_r[4];
  #pragma unroll
  for (int r = 0; r < 4; r++) { m_r[r] = -1e30f; l_r[r] = 0.f; }

  const short* kb = kbf  + ((size_t)(b * HKV_ + kh)) * S_ * HD_;
  const short* vb = vtbf + ((size_t)(b * HKV_ + kh)) * HD_ * S_;

  // staging map (identical coverage to round-9): chunks tid and 256+tid
  const int rr0 = tid >> 3;            // 0..31
  const int ch0 = (tid & 7) * 8;
  const int rr1 = 32 + rr0;            // 32..63

  // prologue: load KV tile 0 into registers
  short8v kr0 = *(const short8v*)(kb + (size_t)rr0 * HD_ + ch0);
  short8v kr1 = *(const short8v*)(kb + (size_t)rr1 * HD_ + ch0);
  short8v vr0 = *(const short8v*)(vb + (size_t)rr0 * S_ + ch0);
  short8v vr1 = *(const short8v*)(vb + (size_t)rr1 * S_ + ch0);

  for (int jt = 0; jt <= qb; jt++) {
    const int j0 = jt * 64;
    __syncthreads();                       // all waves done reading prev tile's LDS
    *(short8v*)(&sK[rr0 * KPAD + ch0])  = kr0;   // compiler inserts vmcnt wait
    *(short8v*)(&sK[rr1 * KPAD + ch0])  = kr1;
    *(short8v*)(&sVt[rr0 * KPAD + ch0]) = vr0;
    *(short8v*)(&sVt[rr1 * KPAD + ch0]) = vr1;
    __syncthreads();                       // tile jt LDS ready

    if (jt < qb) {                         // issue tile jt+1 loads; hide under compute
      const int j0n = j0 + 64;
      kr0 = *(const short8v*)(kb + (size_t)(j0n + rr0) * HD_ + ch0);
      kr1 = *(const short8v*)(kb + (size_t)(j0n + rr1) * HD_ + ch0);
      vr0 = *(const short8v*)(vb + (size_t)rr0 * S_ + j0n + ch0);
      vr1 = *(const short8v*)(vb + (size_t)rr1 * S_ + j0n + ch0);
    }

    float4v sc[4] = {};
    #pragma unroll
    for (int ct = 0; ct < 4; ct++) {
      short8v k0 = *(const short8v*)(&sK[(ct * 16 + cc) * KPAD + g * 8]);
      short8v k1 = *(const short8v*)(&sK[(ct * 16 + cc) * KPAD + g * 8 + 32]);
      __builtin_amdgcn_s_setprio(1);
      sc[ct] = __builtin_amdgcn_mfma_f32_16x16x32_bf16(qf0, k0, sc[ct], 0, 0, 0);
      sc[ct] = __builtin_amdgcn_mfma_f32_16x16x32_bf16(qf1, k1, sc[ct], 0, 0, 0);
      __builtin_amdgcn_s_setprio(0);
    }
    if (jt == qb) {
      #pragma unroll
      for (int ct = 0; ct < 4; ct++)
        #pragma unroll
        for (int r = 0; r < 4; r++)
          if (j0 + ct * 16 + cc > q0 + wv * 16 + g * 4 + r) sc[ct][r] = -1e30f;
    }
    float corr[4];
    #pragma unroll
    for (int r = 0; r < 4; r++) {
      float pm = fmaxf(fmaxf(sc[0][r], sc[1][r]), fmaxf(sc[2][r], sc[3][r]));
      pm = fmaxf(pm, __shfl_xor(pm, 1, 64));
      pm = fmaxf(pm, __shfl_xor(pm, 2, 64));
      pm = fmaxf(pm, __shfl_xor(pm, 4, 64));
      pm = fmaxf(pm, __shfl_xor(pm, 8, 64));
      float mn = fmaxf(m_r[r], pm);
      corr[r] = __expf(m_r[r] - mn);
      m_r[r] = mn;
      float rs = 0.f;
      #pragma unroll
      for (int ct = 0; ct < 4; ct++) {
        float p = __expf(sc[ct][r] - mn);
        sc[ct][r] = p;
        rs += p;
      }
      rs += __shfl_xor(rs, 1, 64);
      rs += __shfl_xor(rs, 2, 64);
      rs += __shfl_xor(rs, 4, 64);
      rs += __shfl_xor(rs, 8, 64);
      l_r[r] = l_r[r] * corr[r] + rs;
    }
    #pragma unroll
    for (int ct = 0; ct < 4; ct++)
      #pragma unroll
      for (int r = 0; r < 4; r++)
        sP[wv][(g * 4 + r) * KPAD + ct * 16 + cc] = f2bf(sc[ct][r]);
    #pragma unroll
    for (int dt = 0; dt < 4; dt++)
      #pragma unroll
      for (int r = 0; r < 4; r++)
        accO[dt][r] *= corr[r];
    short8v pf0 = *(const short8v*)(&sP[wv][cc * KPAD + g * 8]);
    short8v pf1 = *(const short8v*)(&sP[wv][cc * KPAD + g * 8 + 32]);
    #pragma unroll
    for (int dt = 0; dt < 4; dt++) {
      short8v v0 = *(const short8v*)(&sVt[(dt * 16 + cc) * KPAD + g * 8]);
      short8v v1 = *(const short8v*)(&sVt[(dt * 16 + cc) * KPAD + g * 8 + 32]);
      __builtin_amdgcn_s_setprio(1);
      accO[dt] = __builtin_amdgcn_mfma_f32_16x16x32_bf16(pf0, v0, accO[dt], 0, 0, 0);
      accO[dt] = __builtin_amdgcn_mfma_f32_16x16x32_bf16(pf1, v1, accO[dt], 0, 0, 0);
      __builtin_amdgcn_s_setprio(0);
    }
  }
  #pragma unroll
  for (int dt = 0; dt < 4; dt++)
    #pragma unroll
    for (int r = 0; r < 4; r++) {
      int q = q0 + wv * 16 + g * 4 + r;
      obf[((size_t)(b * S_ + q)) * 2048 + h * 64 + dt * 16 + cc] = f2bf(accO[dt][r] / l_r[r]);
    }
}

// ---------------- launch ----------------
extern "C" void kernel_launch(void* const* d_in, const int* in_sizes, int n_in,
                              void* d_out, int out_size, void* d_ws, size_t ws_size,
                              hipStream_t stream) {
  const int*   ids   = (const int*)d_in[0];
  const int*   pos   = (const int*)d_in[1];
  const float* embed = (const float*)d_in[2];
  const float* w_qkv = (const float*)d_in[3];
  const float* w_o   = (const float*)d_in[4];
  const float* w_gu  = (const float*)d_in[5];
  const float* w_dn  = (const float*)d_in[6];
  const float* ln1   = (const float*)d_in[7];
  const float* ln2   = (const float*)d_in[8];
  const float* normw = (const float*)d_in[9];
  float* out = (float*)d_out;

  char* p = (char*)d_ws;
  short* wT    = (short*)p; p += (size_t)11264 * 2048 * 2;
  float* h     = (float*)p; p += (size_t)T_ * D_ * 4;
  float* res   = (float*)p; p += (size_t)T_ * D_ * 4;
  short* hnbf  = (short*)p; p += (size_t)T_ * D_ * 2;
  short* obf   = (short*)p; p += (size_t)T_ * D_ * 2;
  short* mlpbf = (short*)p; p += (size_t)T_ * I_ * 2;
  float* tab   = (float*)p; p += (size_t)T_ * 64 * 4;
  short* qbf   = (short*)p; p += (size_t)B_ * HQ_ * S_ * HD_ * 2;
  short* kbf   = (short*)p; p += (size_t)B_ * HKV_ * S_ * HD_ * 2;
  short* vbf   = (short*)p; p += (size_t)B_ * HKV_ * S_ * HD_ * 2;
  short* vtbf  = (short*)p; p += (size_t)B_ * HKV_ * HD_ * S_ * 2;

  embed_gather<<<T_ * D_ / 4 / 256, 256, 0, stream>>>(ids, embed, h);
  rope_table<<<T_ * 32 / 256, 256, 0, stream>>>(pos, tab);

  for (int l = 0; l < L_; l++) {
    rmsnorm_add<<<T_, 256, 0, stream>>>(h, res, ln1 + l * D_, hnbf, l == 0 ? 1 : 0, 1);

    transpose_bf16<<<dim3(3072 / 64, 2048 / 64), 256, 0, stream>>>(
        w_qkv + (size_t)l * 2048 * 3072, wT, 2048, 3072);
    gemm_qkv_big<<<dim3(3072 / 128, T_ / 128), 512, 0, stream>>>(
        hnbf, wT, tab, qbf, kbf, vbf, 2048);

    transpose_v<<<dim3(16, 8, 2), 256, 0, stream>>>(vbf, vtbf);
    attn_mfma<<<dim3(16, 32, 2), 256, 0, stream>>>(qbf, kbf, vtbf, obf);

    transpose_bf16<<<dim3(2048 / 64, 2048 / 64), 256, 0, stream>>>(
        w_o + (size_t)l * 2048 * 2048, wT, 2048, 2048);
    gemm_big128<<<dim3(2048 / 128, T_ / 128), 512, 0, stream>>>(
        obf, wT, h, T_, 2048, 2048);

    rmsnorm_add<<<T_, 256, 0, stream>>>(h, res, ln2 + l * D_, hnbf, 0, 1);

    transpose_bf16<<<dim3(11264 / 64, 2048 / 64), 256, 0, stream>>>(
        w_gu + (size_t)l * 2048 * 11264, wT, 2048, 11264);
    gemm_glu_big<<<dim3(I_ / 128, T_ / 128), 512, 0, stream>>>(
        hnbf, wT, mlpbf, 2048);

    transpose_bf16<<<dim3(2048 / 64, 5632 / 64), 256, 0, stream>>>(
        w_dn + (size_t)l * 5632 * 2048, wT, 5632, 2048);
    gemm_big128<<<dim3(2048 / 128, T_ / 128), 512, 0, stream>>>(
        mlpbf, wT, h, T_, 2048, 5632);
  }
  rmsnorm_add<<<T_, 256, 0, stream>>>(h, res, normw, out, 0, 0);
}

// Round 11
// 1738.704 us; speedup vs baseline: 1.1600x; 1.0007x over previous
//
#include <hip/hip_runtime.h>
#include <hip/hip_bf16.h>

#define B_ 2
#define S_ 1024
#define T_ (B_*S_)
#define D_ 2048
#define L_ 4
#define HQ_ 32
#define HKV_ 8
#define HD_ 64
#define I_ 5632
#define EPS_ 1e-5f
#define SCALE_ 0.125f

typedef __attribute__((ext_vector_type(4))) float  float4v;
typedef __attribute__((ext_vector_type(8))) short  short8v;

#define GLOAD16(g, l) \
  __builtin_amdgcn_global_load_lds((const __attribute__((address_space(1))) void*)(g), \
                                   (__attribute__((address_space(3))) void*)(l), 16, 0, 0)

__device__ __forceinline__ short f2bf(float f) {
  union { float f; unsigned u; } c; c.f = f;
  unsigned u = c.u + 0x7fffu + ((c.u >> 16) & 1u);
  return (short)(u >> 16);
}

// bijective XCD-aware block swizzle (m204), column-major decode
__device__ __forceinline__ void xcd_swizzle(int gx, int gy, int& bx, int& by) {
  int nwg = gx * gy;
  int orig = by * gx + bx;
  int q = nwg >> 3, r = nwg & 7;
  int xcd = orig & 7, loc = orig >> 3;
  int swz = (xcd < r ? xcd * (q + 1) : r * (q + 1) + (xcd - r) * q) + loc;
  bx = swz / gy;
  by = swz - bx * gy;
}

// ---------------- transpose f32 [K][N] -> bf16 [N][K], 64x64 vectorized ----------------
__global__ __launch_bounds__(256)
void transpose_bf16(const float* __restrict__ in, short* __restrict__ out,
                    int K, int N) {
  __shared__ float t[64][65];
  const int bx = blockIdx.x * 64;   // N
  const int by = blockIdx.y * 64;   // K
  const int tid = threadIdx.x;
  const int lr = tid >> 4;
  const int lc = (tid & 15) * 4;
  #pragma unroll
  for (int j = 0; j < 64; j += 16) {
    float4v v = *(const float4v*)(in + (size_t)(by + lr + j) * N + bx + lc);
    t[lr + j][lc] = v[0]; t[lr + j][lc + 1] = v[1];
    t[lr + j][lc + 2] = v[2]; t[lr + j][lc + 3] = v[3];
  }
  __syncthreads();
  const int nr = tid >> 3;
  const int kc = (tid & 7) * 8;
  #pragma unroll
  for (int j = 0; j < 64; j += 32) {
    short8v y;
    #pragma unroll
    for (int e = 0; e < 8; e++) y[e] = f2bf(t[kc + e][nr + j]);
    *(short8v*)(out + (size_t)(bx + nr + j) * K + by + kc) = y;
  }
}

// ---------------- embedding gather ----------------
__global__ __launch_bounds__(256)
void embed_gather(const int* __restrict__ ids, const float* __restrict__ embed,
                  float* __restrict__ h) {
  size_t i = (size_t)blockIdx.x * 256 + threadIdx.x;
  int t  = (int)(i >> 9);
  int d4 = (int)(i & 511);
  ((float4v*)h)[i] = ((const float4v*)(embed + (size_t)ids[t] * D_))[d4];
}

// ------- RMSNorm: first -> res = x, else pure read of res; out f32/bf16 -------
__global__ __launch_bounds__(256)
void rmsnorm_kernel(const float* __restrict__ x, float* __restrict__ res,
                    const float* __restrict__ w, void* __restrict__ outp,
                    int first, int bf16out) {
  const int row = blockIdx.x;
  const int tid = threadIdx.x;
  const size_t base = (size_t)row * D_;
  float4v v0, v1;
  if (first) {
    v0 = ((const float4v*)(x + base))[tid * 2];
    v1 = ((const float4v*)(x + base))[tid * 2 + 1];
    ((float4v*)(res + base))[tid * 2]     = v0;
    ((float4v*)(res + base))[tid * 2 + 1] = v1;
  } else {
    v0 = ((const float4v*)(res + base))[tid * 2];
    v1 = ((const float4v*)(res + base))[tid * 2 + 1];
  }
  float ss = v0[0]*v0[0] + v0[1]*v0[1] + v0[2]*v0[2] + v0[3]*v0[3]
           + v1[0]*v1[0] + v1[1]*v1[1] + v1[2]*v1[2] + v1[3]*v1[3];
  #pragma unroll
  for (int off = 32; off > 0; off >>= 1) ss += __shfl_xor(ss, off, 64);
  __shared__ float red[4];
  if ((tid & 63) == 0) red[tid >> 6] = ss;
  __syncthreads();
  float tot = red[0] + red[1] + red[2] + red[3];
  float rs = rsqrtf(tot * (1.0f / D_) + EPS_);
  float4v w0 = ((const float4v*)w)[tid * 2];
  float4v w1 = ((const float4v*)w)[tid * 2 + 1];
  float4v o0 = v0 * rs * w0;
  float4v o1 = v1 * rs * w1;
  if (bf16out) {
    short8v y;
    #pragma unroll
    for (int k = 0; k < 4; k++) { y[k] = f2bf(o0[k]); y[k + 4] = f2bf(o1[k]); }
    ((short8v*)((char*)outp + base * 2))[tid] = y;
  } else {
    float* op = (float*)outp + base;
    ((float4v*)op)[tid * 2]     = o0;
    ((float4v*)op)[tid * 2 + 1] = o1;
  }
}

// ======== 128x128 8-wave GEMM, counted vmcnt(4) + T2 swizzle + setprio ========
// LDS 64KB dbuf -> 2 blocks/CU.  Wave tile 64x32 (2M x 4N waves).
// addto=1: C += acc (residual accumulation, o-proj / down-proj).
__global__ __launch_bounds__(512, 4)
void gemm_big128(const short* __restrict__ A, const short* __restrict__ Bt,
                 float* __restrict__ C, int M, int N, int K, int addto) {
  __shared__ short sA[2][128 * 64];
  __shared__ short sB[2][128 * 64];
  int bx = blockIdx.x, by = blockIdx.y;
  xcd_swizzle(gridDim.x, gridDim.y, bx, by);
  const int tid  = threadIdx.x;
  const int lane = tid & 63;
  const int wv   = tid >> 6;
  const int wr   = wv >> 2;          // 0..1
  const int wc   = wv & 3;           // 0..3
  const int row0 = by * 128;
  const int col0 = bx * 128;
  const int fr = lane & 15;
  const int g  = lane >> 4;
  const int NT = K >> 6;

  float4v acc[4][2] = {};            // 32 VGPR

  int rS[2], cS[2];
  #pragma unroll
  for (int k = 0; k < 2; k++) {
    int s = tid + k * 512;
    rS[k] = s >> 3;
    cS[k] = (((s & 7) ^ (rS[k] & 7)) << 3);   // pre-swizzled source col
  }

#define STAGE128(t, buf) do { \
    int k0_ = (t) << 6; \
    _Pragma("unroll") \
    for (int k_ = 0; k_ < 2; k_++) \
      GLOAD16(A  + (size_t)(row0 + rS[k_]) * K + k0_ + cS[k_], \
              &sA[buf][(tid + k_ * 512) * 8]); \
    _Pragma("unroll") \
    for (int k_ = 0; k_ < 2; k_++) \
      GLOAD16(Bt + (size_t)(col0 + rS[k_]) * K + k0_ + cS[k_], \
              &sB[buf][(tid + k_ * 512) * 8]); \
  } while (0)

  STAGE128(0, 0);

  for (int t = 0; t < NT; t++) {
    const int cur = t & 1;
    if (t + 1 < NT) {
      STAGE128(t + 1, cur ^ 1);
      asm volatile("s_waitcnt vmcnt(4)" ::: "memory");
    } else {
      asm volatile("s_waitcnt vmcnt(0)" ::: "memory");
    }
    __builtin_amdgcn_s_barrier();
    __builtin_amdgcn_sched_barrier(0);

    const short* pA = &sA[cur][(wr * 64) * 64];
    const short* pB = &sB[cur][(wc * 32) * 64];
    #pragma unroll
    for (int ks = 0; ks < 2; ks++) {
      const int fswk = ((((ks << 2) | g) ^ (fr & 7)) << 3);
      short8v bfr[2], afr[4];
      #pragma unroll
      for (int ni = 0; ni < 2; ni++)
        bfr[ni] = *(const short8v*)(pB + (ni * 16 + fr) * 64 + fswk);
      #pragma unroll
      for (int m4 = 0; m4 < 4; m4++)
        afr[m4] = *(const short8v*)(pA + (m4 * 16 + fr) * 64 + fswk);
      __builtin_amdgcn_s_setprio(1);
      #pragma unroll
      for (int m4 = 0; m4 < 4; m4++)
        #pragma unroll
        for (int ni = 0; ni < 2; ni++)
          acc[m4][ni] = __builtin_amdgcn_mfma_f32_16x16x32_bf16(
              afr[m4], bfr[ni], acc[m4][ni], 0, 0, 0);
      __builtin_amdgcn_s_setprio(0);
    }
    asm volatile("" ::: "memory");
    __builtin_amdgcn_s_barrier();
  }

  #pragma unroll
  for (int m4 = 0; m4 < 4; m4++)
    #pragma unroll
    for (int ni = 0; ni < 2; ni++) {
      size_t base = (size_t)(row0 + wr * 64 + m4 * 16 + g * 4) * N
                    + col0 + wc * 32 + ni * 16 + fr;
      if (addto) {
        #pragma unroll
        for (int r = 0; r < 4; r++)
          C[base + (size_t)r * N] += acc[m4][ni][r];
      } else {
        #pragma unroll
        for (int r = 0; r < 4; r++)
          C[base + (size_t)r * N] = acc[m4][ni][r];
      }
    }
#undef STAGE128
}

// ======== gate_up GEMM + fused SwiGLU on the same schedule, vmcnt(6) ========
__global__ __launch_bounds__(512, 2)
void gemm_glu_big(const short* __restrict__ A, const short* __restrict__ Bt,
                  short* __restrict__ mlp, int K) {
  __shared__ short sA[2][128 * 64];
  __shared__ short sG[2][128 * 64];
  __shared__ short sU[2][128 * 64];
  int bx = blockIdx.x, by = blockIdx.y;
  xcd_swizzle(gridDim.x, gridDim.y, bx, by);
  const int tid  = threadIdx.x;
  const int lane = tid & 63;
  const int wv   = tid >> 6;
  const int wr   = wv >> 2;
  const int wc   = wv & 3;
  const int row0 = by * 128;
  const int col0 = bx * 128;
  const int fr = lane & 15;
  const int g  = lane >> 4;
  const int NT = K >> 6;

  float4v accg[4][2] = {};
  float4v accu[4][2] = {};

  int rS[2], cS[2];
  #pragma unroll
  for (int k = 0; k < 2; k++) {
    int s = tid + k * 512;
    rS[k] = s >> 3;
    cS[k] = (((s & 7) ^ (rS[k] & 7)) << 3);
  }

#define STAGEGLU(t, buf) do { \
    int k0_ = (t) << 6; \
    _Pragma("unroll") \
    for (int k_ = 0; k_ < 2; k_++) \
      GLOAD16(A  + (size_t)(row0 + rS[k_]) * K + k0_ + cS[k_], \
              &sA[buf][(tid + k_ * 512) * 8]); \
    _Pragma("unroll") \
    for (int k_ = 0; k_ < 2; k_++) \
      GLOAD16(Bt + (size_t)(col0 + rS[k_]) * K + k0_ + cS[k_], \
              &sG[buf][(tid + k_ * 512) * 8]); \
    _Pragma("unroll") \
    for (int k_ = 0; k_ < 2; k_++) \
      GLOAD16(Bt + (size_t)(col0 + I_ + rS[k_]) * K + k0_ + cS[k_], \
              &sU[buf][(tid + k_ * 512) * 8]); \
  } while (0)

  STAGEGLU(0, 0);

  for (int t = 0; t < NT; t++) {
    const int cur = t & 1;
    if (t + 1 < NT) {
      STAGEGLU(t + 1, cur ^ 1);
      asm volatile("s_waitcnt vmcnt(6)" ::: "memory");
    } else {
      asm volatile("s_waitcnt vmcnt(0)" ::: "memory");
    }
    __builtin_amdgcn_s_barrier();
    __builtin_amdgcn_sched_barrier(0);

    const short* pA = &sA[cur][(wr * 64) * 64];
    const short* pG = &sG[cur][(wc * 32) * 64];
    const short* pU = &sU[cur][(wc * 32) * 64];
    #pragma unroll
    for (int ks = 0; ks < 2; ks++) {
      const int fswk = ((((ks << 2) | g) ^ (fr & 7)) << 3);
      short8v bg[2], bu[2], afr[4];
      #pragma unroll
      for (int ni = 0; ni < 2; ni++) {
        bg[ni] = *(const short8v*)(pG + (ni * 16 + fr) * 64 + fswk);
        bu[ni] = *(const short8v*)(pU + (ni * 16 + fr) * 64 + fswk);
      }
      #pragma unroll
      for (int m4 = 0; m4 < 4; m4++)
        afr[m4] = *(const short8v*)(pA + (m4 * 16 + fr) * 64 + fswk);
      __builtin_amdgcn_s_setprio(1);
      #pragma unroll
      for (int m4 = 0; m4 < 4; m4++)
        #pragma unroll
        for (int ni = 0; ni < 2; ni++) {
          accg[m4][ni] = __builtin_amdgcn_mfma_f32_16x16x32_bf16(
              afr[m4], bg[ni], accg[m4][ni], 0, 0, 0);
          accu[m4][ni] = __builtin_amdgcn_mfma_f32_16x16x32_bf16(
              afr[m4], bu[ni], accu[m4][ni], 0, 0, 0);
        }
      __builtin_amdgcn_s_setprio(0);
    }
    asm volatile("" ::: "memory");
    __builtin_amdgcn_s_barrier();
  }

  #pragma unroll
  for (int m4 = 0; m4 < 4; m4++)
    #pragma unroll
    for (int ni = 0; ni < 2; ni++) {
      size_t base = (size_t)(row0 + wr * 64 + m4 * 16 + g * 4) * I_
                    + col0 + wc * 32 + ni * 16 + fr;
      #pragma unroll
      for (int r = 0; r < 4; r++) {
        float gv = accg[m4][ni][r], uv = accu[m4][ni][r];
        mlp[base + (size_t)r * I_] = f2bf(gv / (1.0f + __expf(-gv)) * uv);
      }
    }
#undef STAGEGLU
}

// ======== QKV GEMM on the counted-vmcnt schedule + fused RoPE epilogue ========
__global__ __launch_bounds__(512, 4)
void gemm_qkv_big(const short* __restrict__ A, const short* __restrict__ Bt,
                  const float* __restrict__ tab, short* __restrict__ qbf,
                  short* __restrict__ kbf, short* __restrict__ vbf, int K) {
  __shared__ short sA[2][128 * 64];
  __shared__ short sB[2][128 * 64];
  int bx = blockIdx.x, by = blockIdx.y;
  xcd_swizzle(gridDim.x, gridDim.y, bx, by);
  const int tid  = threadIdx.x;
  const int lane = tid & 63;
  const int wv   = tid >> 6;
  const int wm   = (wv >> 1) * 32;   // 4 M quarters of 32 rows
  const int wn   = (wv & 1) * 64;    // 2 N halves of 64 cols (one head)
  const int row0 = by * 128;
  const int col0 = bx * 128;
  const int fr = lane & 15;
  const int g  = lane >> 4;
  const int NT = K >> 6;

  float4v acc[2][4] = {};            // 32 VGPR

  int rS[2], cS[2];
  #pragma unroll
  for (int k = 0; k < 2; k++) {
    int s = tid + k * 512;
    rS[k] = s >> 3;
    cS[k] = (((s & 7) ^ (rS[k] & 7)) << 3);
  }

#define STAGEQKV(t, buf) do { \
    int k0_ = (t) << 6; \
    _Pragma("unroll") \
    for (int k_ = 0; k_ < 2; k_++) \
      GLOAD16(A  + (size_t)(row0 + rS[k_]) * K + k0_ + cS[k_], \
              &sA[buf][(tid + k_ * 512) * 8]); \
    _Pragma("unroll") \
    for (int k_ = 0; k_ < 2; k_++) \
      GLOAD16(Bt + (size_t)(col0 + rS[k_]) * K + k0_ + cS[k_], \
              &sB[buf][(tid + k_ * 512) * 8]); \
  } while (0)

  STAGEQKV(0, 0);

  for (int t = 0; t < NT; t++) {
    const int cur = t & 1;
    if (t + 1 < NT) {
      STAGEQKV(t + 1, cur ^ 1);
      asm volatile("s_waitcnt vmcnt(4)" ::: "memory");
    } else {
      asm volatile("s_waitcnt vmcnt(0)" ::: "memory");
    }
    __builtin_amdgcn_s_barrier();
    __builtin_amdgcn_sched_barrier(0);

    const short* pA = &sA[cur][wm * 64];
    const short* pB = &sB[cur][wn * 64];
    #pragma unroll
    for (int ks = 0; ks < 2; ks++) {
      const int fswk = ((((ks << 2) | g) ^ (fr & 7)) << 3);
      short8v afr[2], bfr[4];
      #pragma unroll
      for (int m2 = 0; m2 < 2; m2++)
        afr[m2] = *(const short8v*)(pA + (m2 * 16 + fr) * 64 + fswk);
      #pragma unroll
      for (int ni = 0; ni < 4; ni++)
        bfr[ni] = *(const short8v*)(pB + (ni * 16 + fr) * 64 + fswk);
      __builtin_amdgcn_s_setprio(1);
      #pragma unroll
      for (int m2 = 0; m2 < 2; m2++)
        #pragma unroll
        for (int ni = 0; ni < 4; ni++)
          acc[m2][ni] = __builtin_amdgcn_mfma_f32_16x16x32_bf16(
              afr[m2], bfr[ni], acc[m2][ni], 0, 0, 0);
      __builtin_amdgcn_s_setprio(0);
    }
    asm volatile("" ::: "memory");
    __builtin_amdgcn_s_barrier();
  }

  const int head = (col0 + wn) >> 6;
  if (head < HQ_ + HKV_) {
    const float sc = (head < HQ_) ? SCALE_ : 1.0f;
    short* dst = (head < HQ_) ? qbf : kbf;
    const int hh = (head < HQ_) ? head : head - HQ_;
    const int HN = (head < HQ_) ? HQ_ : HKV_;
    #pragma unroll
    for (int m2 = 0; m2 < 2; m2++)
      #pragma unroll
      for (int jj = 0; jj < 2; jj++)
        #pragma unroll
        for (int r = 0; r < 4; r++) {
          int m = row0 + wm + m2 * 16 + g * 4 + r;
          int b = m >> 10, s = m & (S_ - 1);
          int d1 = jj * 16 + fr;
          float x1 = acc[m2][jj][r], x2 = acc[m2][jj + 2][r];
          const float* tb = tab + (size_t)m * 64 + d1 * 2;
          float c = tb[0], sn = tb[1];
          size_t base = ((size_t)((b * HN + hh) * S_ + s)) * HD_;
          dst[base + d1]      = f2bf((x1 * c - x2 * sn) * sc);
          dst[base + d1 + 32] = f2bf((x2 * c + x1 * sn) * sc);
        }
  } else {
    const int vh = head - HQ_ - HKV_;
    #pragma unroll
    for (int m2 = 0; m2 < 2; m2++)
      #pragma unroll
      for (int ni = 0; ni < 4; ni++)
        #pragma unroll
        for (int r = 0; r < 4; r++) {
          int m = row0 + wm + m2 * 16 + g * 4 + r;
          int b = m >> 10, s = m & (S_ - 1);
          vbf[((size_t)((b * HKV_ + vh) * S_ + s)) * HD_ + ni * 16 + fr] =
              f2bf(acc[m2][ni][r]);
        }
  }
#undef STAGEQKV
}

// ---------------- RoPE cos/sin table: [T][32][2] f32 ----------------
__global__ __launch_bounds__(256)
void rope_table(const int* __restrict__ pos, float* __restrict__ tab) {
  int i = blockIdx.x * 256 + threadIdx.x;
  int t = i >> 5, ii = i & 31;
  float p = (float)pos[t];
  float freq = __expf(-(float)ii * (9.210340371976184f / 32.0f));
  float ang = p * freq;
  tab[2 * i]     = cosf(ang);
  tab[2 * i + 1] = sinf(ang);
}

// ---------------- V transpose: vbf [bkh][j][d] -> vtbf [bkh][d][j] ----------------
#define KPAD 68

__global__ __launch_bounds__(256)
void transpose_v(const short* __restrict__ vbf, short* __restrict__ vtbf) {
  __shared__ short sv[64 * KPAD];
  const int jt = blockIdx.x, kh = blockIdx.y, b = blockIdx.z;
  const int tid = threadIdx.x;
  const short* src = vbf + ((size_t)((b * HKV_ + kh) * S_ + jt * 64)) * HD_;
  #pragma unroll
  for (int it = 0; it < 2; it++) {
    int c = it * 256 + tid;
    int rr = c >> 3, ch = (c & 7) * 8;
    *(short8v*)(&sv[rr * KPAD + ch]) = *(const short8v*)(src + (size_t)rr * HD_ + ch);
  }
  __syncthreads();
  const int dc = tid >> 2;
  const int jc = (tid & 3) * 16;
  short8v o1, o2;
  #pragma unroll
  for (int k = 0; k < 8; k++) o1[k] = sv[(jc + k) * KPAD + dc];
  #pragma unroll
  for (int k = 0; k < 8; k++) o2[k] = sv[(jc + 8 + k) * KPAD + dc];
  short* od = vtbf + ((size_t)((b * HKV_ + kh) * HD_ + dc)) * S_ + jt * 64 + jc;
  *(short8v*)od       = o1;
  *(short8v*)(od + 8) = o2;
}

// ---------------- MFMA flash attention: T14 async-STAGE + T13 defer-max ----------------
__global__ __launch_bounds__(256)
void attn_mfma(const short* __restrict__ qbf, const short* __restrict__ kbf,
               const short* __restrict__ vtbf, short* __restrict__ obf) {
  __shared__ short sK[64 * KPAD];
  __shared__ short sVt[64 * KPAD];
  __shared__ short sP[4][16 * KPAD];
  const int qb = blockIdx.x;
  const int h  = blockIdx.y;
  const int b  = blockIdx.z;
  const int kh = h >> 2;
  const int tid  = threadIdx.x;
  const int lane = tid & 63;
  const int wv   = tid >> 6;
  const int q0 = qb * 64;
  const int cc = lane & 15;
  const int g  = lane >> 4;

  short8v qf0, qf1;
  {
    const short* qrow = qbf + ((size_t)((b * HQ_ + h) * S_ + q0 + wv * 16 + cc)) * HD_;
    qf0 = *(const short8v*)(qrow + g * 8);
    qf1 = *(const short8v*)(qrow + g * 8 + 32);
  }
  float4v accO[4] = {};
  float m_r[4], l_r[4];
  #pragma unroll
  for (int r = 0; r < 4; r++) { m_r[r] = -1e30f; l_r[r] = 0.f; }

  const short* kb = kbf  + ((size_t)(b * HKV_ + kh)) * S_ * HD_;
  const short* vb = vtbf + ((size_t)(b * HKV_ + kh)) * HD_ * S_;

  const int rr0 = tid >> 3;            // 0..31
  const int ch0 = (tid & 7) * 8;
  const int rr1 = 32 + rr0;            // 32..63

  // prologue: load KV tile 0 into registers
  short8v kr0 = *(const short8v*)(kb + (size_t)rr0 * HD_ + ch0);
  short8v kr1 = *(const short8v*)(kb + (size_t)rr1 * HD_ + ch0);
  short8v vr0 = *(const short8v*)(vb + (size_t)rr0 * S_ + ch0);
  short8v vr1 = *(const short8v*)(vb + (size_t)rr1 * S_ + ch0);

  for (int jt = 0; jt <= qb; jt++) {
    const int j0 = jt * 64;
    __syncthreads();                       // all waves done reading prev tile's LDS
    *(short8v*)(&sK[rr0 * KPAD + ch0])  = kr0;   // compiler inserts vmcnt wait
    *(short8v*)(&sK[rr1 * KPAD + ch0])  = kr1;
    *(short8v*)(&sVt[rr0 * KPAD + ch0]) = vr0;
    *(short8v*)(&sVt[rr1 * KPAD + ch0]) = vr1;
    __syncthreads();                       // tile jt LDS ready

    if (jt < qb) {                         // issue tile jt+1 loads; hide under compute
      const int j0n = j0 + 64;
      kr0 = *(const short8v*)(kb + (size_t)(j0n + rr0) * HD_ + ch0);
      kr1 = *(const short8v*)(kb + (size_t)(j0n + rr1) * HD_ + ch0);
      vr0 = *(const short8v*)(vb + (size_t)rr0 * S_ + j0n + ch0);
      vr1 = *(const short8v*)(vb + (size_t)rr1 * S_ + j0n + ch0);
    }

    float4v sc[4] = {};
    #pragma unroll
    for (int ct = 0; ct < 4; ct++) {
      short8v k0 = *(const short8v*)(&sK[(ct * 16 + cc) * KPAD + g * 8]);
      short8v k1 = *(const short8v*)(&sK[(ct * 16 + cc) * KPAD + g * 8 + 32]);
      __builtin_amdgcn_s_setprio(1);
      sc[ct] = __builtin_amdgcn_mfma_f32_16x16x32_bf16(qf0, k0, sc[ct], 0, 0, 0);
      sc[ct] = __builtin_amdgcn_mfma_f32_16x16x32_bf16(qf1, k1, sc[ct], 0, 0, 0);
      __builtin_amdgcn_s_setprio(0);
    }
    if (jt == qb) {
      #pragma unroll
      for (int ct = 0; ct < 4; ct++)
        #pragma unroll
        for (int r = 0; r < 4; r++)
          if (j0 + ct * 16 + cc > q0 + wv * 16 + g * 4 + r) sc[ct][r] = -1e30f;
    }
    // row maxes (rows live in 16-lane groups)
    float pmv[4], dmax = -1e30f;
    #pragma unroll
    for (int r = 0; r < 4; r++) {
      float pm = fmaxf(fmaxf(sc[0][r], sc[1][r]), fmaxf(sc[2][r], sc[3][r]));
      pm = fmaxf(pm, __shfl_xor(pm, 1, 64));
      pm = fmaxf(pm, __shfl_xor(pm, 2, 64));
      pm = fmaxf(pm, __shfl_xor(pm, 4, 64));
      pm = fmaxf(pm, __shfl_xor(pm, 8, 64));
      pmv[r] = pm;
      dmax = fmaxf(dmax, pm - m_r[r]);
    }
    // T13 defer-max: skip rescale when max growth <= 8 across the wave
    if (!__all(dmax <= 8.0f)) {
      float corr[4];
      #pragma unroll
      for (int r = 0; r < 4; r++) {
        float mn = fmaxf(m_r[r], pmv[r]);
        corr[r] = __expf(m_r[r] - mn);
        m_r[r] = mn;
        l_r[r] *= corr[r];
      }
      #pragma unroll
      for (int dt = 0; dt < 4; dt++)
        #pragma unroll
        for (int r = 0; r < 4; r++)
          accO[dt][r] *= corr[r];
    }
    #pragma unroll
    for (int r = 0; r < 4; r++) {
      float rs = 0.f;
      #pragma unroll
      for (int ct = 0; ct < 4; ct++) {
        float p = __expf(sc[ct][r] - m_r[r]);
        sc[ct][r] = p;
        rs += p;
      }
      rs += __shfl_xor(rs, 1, 64);
      rs += __shfl_xor(rs, 2, 64);
      rs += __shfl_xor(rs, 4, 64);
      rs += __shfl_xor(rs, 8, 64);
      l_r[r] += rs;
    }
    #pragma unroll
    for (int ct = 0; ct < 4; ct++)
      #pragma unroll
      for (int r = 0; r < 4; r++)
        sP[wv][(g * 4 + r) * KPAD + ct * 16 + cc] = f2bf(sc[ct][r]);
    short8v pf0 = *(const short8v*)(&sP[wv][cc * KPAD + g * 8]);
    short8v pf1 = *(const short8v*)(&sP[wv][cc * KPAD + g * 8 + 32]);
    #pragma unroll
    for (int dt = 0; dt < 4; dt++) {
      short8v v0 = *(const short8v*)(&sVt[(dt * 16 + cc) * KPAD + g * 8]);
      short8v v1 = *(const short8v*)(&sVt[(dt * 16 + cc) * KPAD + g * 8 + 32]);
      __builtin_amdgcn_s_setprio(1);
      accO[dt] = __builtin_amdgcn_mfma_f32_16x16x32_bf16(pf0, v0, accO[dt], 0, 0, 0);
      accO[dt] = __builtin_amdgcn_mfma_f32_16x16x32_bf16(pf1, v1, accO[dt], 0, 0, 0);
      __builtin_amdgcn_s_setprio(0);
    }
  }
  #pragma unroll
  for (int dt = 0; dt < 4; dt++)
    #pragma unroll
    for (int r = 0; r < 4; r++) {
      int q = q0 + wv * 16 + g * 4 + r;
      obf[((size_t)(b * S_ + q)) * 2048 + h * 64 + dt * 16 + cc] = f2bf(accO[dt][r] / l_r[r]);
    }
}

// ---------------- launch ----------------
extern "C" void kernel_launch(void* const* d_in, const int* in_sizes, int n_in,
                              void* d_out, int out_size, void* d_ws, size_t ws_size,
                              hipStream_t stream) {
  const int*   ids   = (const int*)d_in[0];
  const int*   pos   = (const int*)d_in[1];
  const float* embed = (const float*)d_in[2];
  const float* w_qkv = (const float*)d_in[3];
  const float* w_o   = (const float*)d_in[4];
  const float* w_gu  = (const float*)d_in[5];
  const float* w_dn  = (const float*)d_in[6];
  const float* ln1   = (const float*)d_in[7];
  const float* ln2   = (const float*)d_in[8];
  const float* normw = (const float*)d_in[9];
  float* out = (float*)d_out;

  char* p = (char*)d_ws;
  short* wT    = (short*)p; p += (size_t)11264 * 2048 * 2;
  float* h     = (float*)p; p += (size_t)T_ * D_ * 4;
  float* res   = (float*)p; p += (size_t)T_ * D_ * 4;
  short* hnbf  = (short*)p; p += (size_t)T_ * D_ * 2;
  short* obf   = (short*)p; p += (size_t)T_ * D_ * 2;
  short* mlpbf = (short*)p; p += (size_t)T_ * I_ * 2;
  float* tab   = (float*)p; p += (size_t)T_ * 64 * 4;
  short* qbf   = (short*)p; p += (size_t)B_ * HQ_ * S_ * HD_ * 2;
  short* kbf   = (short*)p; p += (size_t)B_ * HKV_ * S_ * HD_ * 2;
  short* vbf   = (short*)p; p += (size_t)B_ * HKV_ * S_ * HD_ * 2;
  short* vtbf  = (short*)p; p += (size_t)B_ * HKV_ * HD_ * S_ * 2;

  embed_gather<<<T_ * D_ / 4 / 256, 256, 0, stream>>>(ids, embed, h);
  rope_table<<<T_ * 32 / 256, 256, 0, stream>>>(pos, tab);

  for (int l = 0; l < L_; l++) {
    // res holds the running residual (filled by first=1 at l==0, then by
    // GEMM accumulation); rmsnorm is a pure read-normalize after that.
    rmsnorm_kernel<<<T_, 256, 0, stream>>>(h, res, ln1 + l * D_, hnbf,
                                           l == 0 ? 1 : 0, 1);

    transpose_bf16<<<dim3(3072 / 64, 2048 / 64), 256, 0, stream>>>(
        w_qkv + (size_t)l * 2048 * 3072, wT, 2048, 3072);
    gemm_qkv_big<<<dim3(3072 / 128, T_ / 128), 512, 0, stream>>>(
        hnbf, wT, tab, qbf, kbf, vbf, 2048);

    transpose_v<<<dim3(16, 8, 2), 256, 0, stream>>>(vbf, vtbf);
    attn_mfma<<<dim3(16, 32, 2), 256, 0, stream>>>(qbf, kbf, vtbf, obf);

    transpose_bf16<<<dim3(2048 / 64, 2048 / 64), 256, 0, stream>>>(
        w_o + (size_t)l * 2048 * 2048, wT, 2048, 2048);
    gemm_big128<<<dim3(2048 / 128, T_ / 128), 512, 0, stream>>>(
        obf, wT, res, T_, 2048, 2048, 1);          // res += o_proj

    rmsnorm_kernel<<<T_, 256, 0, stream>>>(nullptr, res, ln2 + l * D_, hnbf, 0, 1);

    transpose_bf16<<<dim3(11264 / 64, 2048 / 64), 256, 0, stream>>>(
        w_gu + (size_t)l * 2048 * 11264, wT, 2048, 11264);
    gemm_glu_big<<<dim3(I_ / 128, T_ / 128), 512, 0, stream>>>(
        hnbf, wT, mlpbf, 2048);

    transpose_bf16<<<dim3(2048 / 64, 5632 / 64), 256, 0, stream>>>(
        w_dn + (size_t)l * 5632 * 2048, wT, 5632, 2048);
    gemm_big128<<<dim3(2048 / 128, T_ / 128), 512, 0, stream>>>(
        mlpbf, wT, res, T_, 2048, 5632, 1);        // res += down_proj
  }
  rmsnorm_kernel<<<T_, 256, 0, stream>>>(nullptr, res, normw, out, 0, 0);
}